// Round 3
// baseline (5155.894 us; speedup 1.0000x reference)
//
#include <hip/hip_runtime.h>

#define N_USERS 100000
#define N_ITEMS 50000
#define N_NODES 150000
#define EMB 64
#define NNZ_TOT 4800000
#define BATCH_SZ 4096

#define BROWS 64                 // rows per bucket
#define NB 2344                  // ceil(150000/64)
#define CHUNKS 256
#define CHUNKE 18750             // NNZ_TOT / CHUNKS (exact)
#define OFFS (NB + 1)            // off-table row stride

typedef unsigned short u16;

static __device__ __forceinline__ u16 f2bf(float f) {
    unsigned u = __float_as_uint(f);
    unsigned r = u + 0x7FFFu + ((u >> 16) & 1u);   // RNE
    return (u16)(r >> 16);
}
static __device__ __forceinline__ float bf2f(u16 h) {
    return __uint_as_float(((unsigned)h) << 16);
}

// ---------------- ego0 (bf16) = concat(user, item) ----------------
__global__ void k_init(const float* __restrict__ ue, const float* __restrict__ ie,
                       u16* __restrict__ ego) {
    size_t i = (size_t)blockIdx.x * blockDim.x + threadIdx.x;   // group of 4 elems
    const size_t n4 = (size_t)N_NODES * EMB / 4;
    if (i >= n4) return;
    const size_t u4 = (size_t)N_USERS * EMB / 4;
    float4 v = (i < u4) ? ((const float4*)ue)[i] : ((const float4*)ie)[i - u4];
    ushort4 o;
    o.x = f2bf(v.x); o.y = f2bf(v.y); o.z = f2bf(v.z); o.w = f2bf(v.w);
    ((ushort4*)ego)[i] = o;
}

// ---------------- per-chunk counting-sort of edges into 64-row buckets ----------------
__global__ __launch_bounds__(256) void k_bin(const int* __restrict__ erow,
                                             const int* __restrict__ ecol,
                                             const float* __restrict__ eval_,
                                             int2* __restrict__ pairs,
                                             int* __restrict__ off) {
    __shared__ int hist[NB];
    __shared__ int fill[NB];
    const int c = blockIdx.x;
    const int cbase = c * CHUNKE;
    const int tid = threadIdx.x;

    for (int i = tid; i < NB; i += 256) hist[i] = 0;
    __syncthreads();

    // pass 1: bucket histogram
    for (int i = tid; i < CHUNKE; i += 256)
        atomicAdd(&hist[erow[cbase + i] >> 6], 1);
    __syncthreads();

    // exclusive scan of hist -> fill (wave 0 only)
    if (tid < 64) {
        int carry = 0;
        for (int blk = 0; blk < (NB + 63) / 64; ++blk) {
            int idx = blk * 64 + tid;
            int v = (idx < NB) ? hist[idx] : 0;
            int s = v;
            #pragma unroll
            for (int o = 1; o < 64; o <<= 1) {
                int t = __shfl_up(s, o);
                if (tid >= o) s += t;
            }
            if (idx < NB) fill[idx] = s - v + carry;
            carry += __shfl(s, 63);
        }
    }
    __syncthreads();

    // publish absolute segment offsets
    for (int i = tid; i < NB; i += 256) off[c * OFFS + i] = cbase + fill[i];
    if (tid == 0) off[c * OFFS + NB] = cbase + CHUNKE;
    __syncthreads();

    // pass 2: scatter packed (row_local<<18 | col, val) into chunk-private region
    for (int i = tid; i < CHUNKE; i += 256) {
        int e = cbase + i;
        int r = erow[e];
        int bb = r >> 6;
        int p = atomicAdd(&fill[bb], 1);
        int2 pr;
        pr.x = ((r & 63) << 18) | ecol[e];
        pr.y = __float_as_int(eval_[e]);
        pairs[cbase + p] = pr;
    }
}

// ---------------- SpMV: one block per bucket, LDS f32 accumulator ----------------
__global__ __launch_bounds__(256) void k_spmv(const int* __restrict__ off,
                                              const int2* __restrict__ pairs,
                                              const u16* __restrict__ cur,
                                              u16* __restrict__ nxt) {
    __shared__ float acc[BROWS * EMB];   // 16 KB
    const int b = blockIdx.x;
    const int tid = threadIdx.x, lane = tid & 63, w = tid >> 6;

    for (int i = tid; i < BROWS * EMB; i += 256) acc[i] = 0.f;
    __syncthreads();

    for (int c = w; c < CHUNKS; c += 4) {
        int e0 = off[c * OFFS + b];
        int e1 = off[c * OFFS + b + 1];
        int e = e0;
        for (; e + 3 < e1; e += 4) {
            int2 p0 = pairs[e], p1 = pairs[e + 1], p2 = pairs[e + 2], p3 = pairs[e + 3];
            float x0 = bf2f(cur[((size_t)(p0.x & 0x3FFFF)) * EMB + lane]);
            float x1 = bf2f(cur[((size_t)(p1.x & 0x3FFFF)) * EMB + lane]);
            float x2 = bf2f(cur[((size_t)(p2.x & 0x3FFFF)) * EMB + lane]);
            float x3 = bf2f(cur[((size_t)(p3.x & 0x3FFFF)) * EMB + lane]);
            atomicAdd(&acc[((p0.x >> 18) << 6) + lane], __int_as_float(p0.y) * x0);
            atomicAdd(&acc[((p1.x >> 18) << 6) + lane], __int_as_float(p1.y) * x1);
            atomicAdd(&acc[((p2.x >> 18) << 6) + lane], __int_as_float(p2.y) * x2);
            atomicAdd(&acc[((p3.x >> 18) << 6) + lane], __int_as_float(p3.y) * x3);
        }
        for (; e < e1; ++e) {
            int2 p = pairs[e];
            float x = bf2f(cur[((size_t)(p.x & 0x3FFFF)) * EMB + lane]);
            atomicAdd(&acc[((p.x >> 18) << 6) + lane], __int_as_float(p.y) * x);
        }
    }
    __syncthreads();

    const int rbase = b * BROWS;
    for (int i = tid; i < BROWS * EMB; i += 256) {
        int r = rbase + (i >> 6);
        if (r < N_NODES) nxt[(size_t)r * EMB + (i & 63)] = f2bf(acc[i]);
    }
}

// ---------------- out = layer-0 gather from f32 originals ----------------
__global__ void k_out0(const float* __restrict__ ue, const float* __restrict__ ie,
                       const int* __restrict__ users, const int* __restrict__ pos,
                       const int* __restrict__ neg, float* __restrict__ out) {
    size_t t = (size_t)blockIdx.x * blockDim.x + threadIdx.x;
    size_t r = t >> 4;
    int sub = (int)(t & 15);
    if (r >= (size_t)(3 * BATCH_SZ)) return;
    int which = (int)(r / BATCH_SZ);
    int bi    = (int)(r % BATCH_SZ);
    int node;
    if (which == 0)      node = users[bi];
    else if (which == 1) node = N_USERS + pos[bi];
    else                 node = N_USERS + neg[bi];
    const float* src = (node < N_USERS) ? (ue + (size_t)node * EMB)
                                        : (ie + (size_t)(node - N_USERS) * EMB);
    float4 v = ((const float4*)src)[sub];
    ((float4*)(out + r * EMB))[sub] = v;
}

// ---------------- out += layer-k gather (bf16), optional final scale ----------------
__global__ void k_outb(const u16* __restrict__ ego,
                       const int* __restrict__ users, const int* __restrict__ pos,
                       const int* __restrict__ neg, float* __restrict__ out, float scale) {
    size_t t = (size_t)blockIdx.x * blockDim.x + threadIdx.x;
    size_t r = t >> 4;
    int sub = (int)(t & 15);
    if (r >= (size_t)(3 * BATCH_SZ)) return;
    int which = (int)(r / BATCH_SZ);
    int bi    = (int)(r % BATCH_SZ);
    int node;
    if (which == 0)      node = users[bi];
    else if (which == 1) node = N_USERS + pos[bi];
    else                 node = N_USERS + neg[bi];
    ushort4 h = ((const ushort4*)(ego + (size_t)node * EMB))[sub];
    float4* op = (float4*)(out + r * EMB) + sub;
    float4 o = *op;
    o.x = (o.x + bf2f(h.x)) * scale;
    o.y = (o.y + bf2f(h.y)) * scale;
    o.z = (o.z + bf2f(h.z)) * scale;
    o.w = (o.w + bf2f(h.w)) * scale;
    *op = o;
}

extern "C" void kernel_launch(void* const* d_in, const int* in_sizes, int n_in,
                              void* d_out, int out_size, void* d_ws, size_t ws_size,
                              hipStream_t stream) {
    const int*   erow  = (const int*)  d_in[0];
    const int*   ecol  = (const int*)  d_in[1];
    const float* eval_ = (const float*)d_in[2];
    const float* ue    = (const float*)d_in[3];
    const float* ie    = (const float*)d_in[4];
    const int*   users = (const int*)  d_in[5];
    const int*   pos   = (const int*)  d_in[6];
    const int*   neg   = (const int*)  d_in[7];
    float* out = (float*)d_out;

    char* ws = (char*)d_ws;
    const size_t tblB = (size_t)150016 * EMB * sizeof(u16);      // 19.2 MB (rounded rows)
    u16*  ego0  = (u16*)(ws);
    u16*  ego1  = (u16*)(ws + tblB);
    int2* pairs = (int2*)(ws + 2 * tblB);
    int*  off   = (int*)(ws + 2 * tblB + (size_t)NNZ_TOT * sizeof(int2));

    const int blk = 256;

    // bf16 ego0
    const size_t n4 = (size_t)N_NODES * EMB / 4;                  // 2.4M
    k_init<<<(int)((n4 + blk - 1) / blk), blk, 0, stream>>>(ue, ie, ego0);

    // bucket-binned edge list + per-(chunk,bucket) offsets
    k_bin<<<CHUNKS, blk, 0, stream>>>(erow, ecol, eval_, pairs, off);

    // out = ego0 contribution (exact f32)
    const int grid_g = (int)(((size_t)3 * BATCH_SZ * 16 + blk - 1) / blk);
    k_out0<<<grid_g, blk, 0, stream>>>(ue, ie, users, pos, neg, out);

    // 3 propagation layers
    u16* cur = ego0;
    u16* nxt = ego1;
    for (int layer = 0; layer < 3; ++layer) {
        k_spmv<<<NB, blk, 0, stream>>>(off, pairs, cur, nxt);
        k_outb<<<grid_g, blk, 0, stream>>>(nxt, users, pos, neg, out,
                                           (layer == 2) ? 0.25f : 1.0f);
        u16* tmp = cur; cur = nxt; nxt = tmp;
    }
}

// Round 5
// 1166.073 us; speedup vs baseline: 4.4216x; 4.4216x over previous
//
#include <hip/hip_runtime.h>

#define N_USERS 100000
#define N_ITEMS 50000
#define N_NODES 150000
#define EMB 64
#define NNZ_TOT 4800000
#define BATCH_SZ 4096
#define SCAN_N (N_NODES + 1)

typedef unsigned short u16;

static __device__ __forceinline__ u16 f2bf(float f) {
    unsigned u = __float_as_uint(f);
    unsigned r = u + 0x7FFFu + ((u >> 16) & 1u);   // RNE
    return (u16)(r >> 16);
}
static __device__ __forceinline__ float bf2f(u16 h) {
    return __uint_as_float(((unsigned)h) << 16);
}

// ---------------- ego0 (bf16) = concat(user, item) ----------------
__global__ void k_init(const float* __restrict__ ue, const float* __restrict__ ie,
                       u16* __restrict__ ego) {
    size_t i = (size_t)blockIdx.x * blockDim.x + threadIdx.x;   // group of 4 elems
    const size_t n4 = (size_t)N_NODES * EMB / 4;
    if (i >= n4) return;
    const size_t u4 = (size_t)N_USERS * EMB / 4;
    float4 v = (i < u4) ? ((const float4*)ue)[i] : ((const float4*)ie)[i - u4];
    ushort4 o;
    o.x = f2bf(v.x); o.y = f2bf(v.y); o.z = f2bf(v.z); o.w = f2bf(v.w);
    ((ushort4*)ego)[i] = o;
}

// ---------------- zero deg + fill counters ----------------
__global__ void k_zero(int* __restrict__ p, int n) {
    int i = blockIdx.x * blockDim.x + threadIdx.x;
    if (i < n) p[i] = 0;
}

// ---------------- histogram of destination rows ----------------
__global__ void k_hist(const int* __restrict__ erow, int* __restrict__ deg) {
    int e = blockIdx.x * blockDim.x + threadIdx.x;
    if (e >= NNZ_TOT) return;
    atomicAdd(&deg[erow[e]], 1);
}

// ---------------- single-block exclusive scan: rowptr[0..N_NODES] ----------------
__global__ __launch_bounds__(1024) void k_scan(const int* __restrict__ deg,
                                               int* __restrict__ rowptr) {
    __shared__ int lds[1024];
    __shared__ int carry_s;
    const int tid = threadIdx.x;
    if (tid == 0) carry_s = 0;
    __syncthreads();
    for (int base = 0; base < SCAN_N; base += 1024 * 8) {
        int vals[8];
        int local = 0;
        #pragma unroll
        for (int j = 0; j < 8; ++j) {
            int idx = base + tid * 8 + j;
            int v = (idx < N_NODES) ? deg[idx] : 0;
            vals[j] = local;            // exclusive within thread
            local += v;
        }
        lds[tid] = local;
        __syncthreads();
        for (int off = 1; off < 1024; off <<= 1) {
            int t = (tid >= off) ? lds[tid - off] : 0;
            __syncthreads();
            lds[tid] += t;
            __syncthreads();
        }
        int thread_excl = lds[tid] - local;
        int carry = carry_s;
        int total = lds[1023];
        #pragma unroll
        for (int j = 0; j < 8; ++j) {
            int idx = base + tid * 8 + j;
            if (idx < SCAN_N) rowptr[idx] = carry + thread_excl + vals[j];
        }
        __syncthreads();
        if (tid == 0) carry_s = carry + total;
        __syncthreads();
    }
}

// ---------------- fill row-sorted (col,val) pairs ----------------
__global__ void k_fill(const int* __restrict__ erow,
                       const int* __restrict__ ecol,
                       const float* __restrict__ eval_,
                       const int* __restrict__ rowptr,
                       int* __restrict__ fill,
                       int2* __restrict__ pairs) {
    int e = blockIdx.x * blockDim.x + threadIdx.x;
    if (e >= NNZ_TOT) return;
    int r = erow[e];
    int pos = atomicAdd(&fill[r], 1);
    int idx = rowptr[r] + pos;
    int2 p;
    p.x = ecol[e];
    p.y = __float_as_int(eval_[e]);
    pairs[idx] = p;
}

// ---------------- SpMV: one wave per row, lane = emb element, bf16 tables ----------------
__global__ __launch_bounds__(256) void k_spmv(const int* __restrict__ rowptr,
                                              const int2* __restrict__ pairs,
                                              const u16* __restrict__ cur,
                                              u16* __restrict__ nxt) {
    size_t gid = (size_t)blockIdx.x * blockDim.x + threadIdx.x;
    int row  = (int)(gid >> 6);
    int lane = (int)(gid & 63);
    if (row >= N_NODES) return;
    int start = rowptr[row];
    int end   = rowptr[row + 1];
    float a0 = 0.f, a1 = 0.f, a2 = 0.f, a3 = 0.f;
    int e = start;
    for (; e + 3 < end; e += 4) {
        int2 q0 = pairs[e], q1 = pairs[e + 1], q2 = pairs[e + 2], q3 = pairs[e + 3];
        // pair words are wave-uniform (row is wave-uniform) -> scalarize
        int c0 = __builtin_amdgcn_readfirstlane(q0.x);
        float v0 = __uint_as_float(__builtin_amdgcn_readfirstlane(q0.y));
        int c1 = __builtin_amdgcn_readfirstlane(q1.x);
        float v1 = __uint_as_float(__builtin_amdgcn_readfirstlane(q1.y));
        int c2 = __builtin_amdgcn_readfirstlane(q2.x);
        float v2 = __uint_as_float(__builtin_amdgcn_readfirstlane(q2.y));
        int c3 = __builtin_amdgcn_readfirstlane(q3.x);
        float v3 = __uint_as_float(__builtin_amdgcn_readfirstlane(q3.y));
        a0 += v0 * bf2f(cur[(size_t)c0 * EMB + lane]);
        a1 += v1 * bf2f(cur[(size_t)c1 * EMB + lane]);
        a2 += v2 * bf2f(cur[(size_t)c2 * EMB + lane]);
        a3 += v3 * bf2f(cur[(size_t)c3 * EMB + lane]);
    }
    for (; e < end; ++e) {
        int2 q = pairs[e];
        int c = __builtin_amdgcn_readfirstlane(q.x);
        float v = __uint_as_float(__builtin_amdgcn_readfirstlane(q.y));
        a0 += v * bf2f(cur[(size_t)c * EMB + lane]);
    }
    nxt[(size_t)row * EMB + lane] = f2bf((a0 + a1) + (a2 + a3));
}

// ---------------- out = layer-0 gather from f32 originals (exact) ----------------
__global__ void k_out0(const float* __restrict__ ue, const float* __restrict__ ie,
                       const int* __restrict__ users, const int* __restrict__ pos,
                       const int* __restrict__ neg, float* __restrict__ out) {
    size_t t = (size_t)blockIdx.x * blockDim.x + threadIdx.x;
    size_t r = t >> 4;
    int sub = (int)(t & 15);
    if (r >= (size_t)(3 * BATCH_SZ)) return;
    int which = (int)(r / BATCH_SZ);
    int bi    = (int)(r % BATCH_SZ);
    int node;
    if (which == 0)      node = users[bi];
    else if (which == 1) node = N_USERS + pos[bi];
    else                 node = N_USERS + neg[bi];
    const float* src = (node < N_USERS) ? (ue + (size_t)node * EMB)
                                        : (ie + (size_t)(node - N_USERS) * EMB);
    float4 v = ((const float4*)src)[sub];
    ((float4*)(out + r * EMB))[sub] = v;
}

// ---------------- out += layer-k gather (bf16), optional final scale ----------------
__global__ void k_outb(const u16* __restrict__ ego,
                       const int* __restrict__ users, const int* __restrict__ pos,
                       const int* __restrict__ neg, float* __restrict__ out, float scale) {
    size_t t = (size_t)blockIdx.x * blockDim.x + threadIdx.x;
    size_t r = t >> 4;
    int sub = (int)(t & 15);
    if (r >= (size_t)(3 * BATCH_SZ)) return;
    int which = (int)(r / BATCH_SZ);
    int bi    = (int)(r % BATCH_SZ);
    int node;
    if (which == 0)      node = users[bi];
    else if (which == 1) node = N_USERS + pos[bi];
    else                 node = N_USERS + neg[bi];
    ushort4 h = ((const ushort4*)(ego + (size_t)node * EMB))[sub];
    float4* op = (float4*)(out + r * EMB) + sub;
    float4 o = *op;
    o.x = (o.x + bf2f(h.x)) * scale;
    o.y = (o.y + bf2f(h.y)) * scale;
    o.z = (o.z + bf2f(h.z)) * scale;
    o.w = (o.w + bf2f(h.w)) * scale;
    *op = o;
}

extern "C" void kernel_launch(void* const* d_in, const int* in_sizes, int n_in,
                              void* d_out, int out_size, void* d_ws, size_t ws_size,
                              hipStream_t stream) {
    const int*   erow  = (const int*)  d_in[0];
    const int*   ecol  = (const int*)  d_in[1];
    const float* eval_ = (const float*)d_in[2];
    const float* ue    = (const float*)d_in[3];
    const float* ie    = (const float*)d_in[4];
    const int*   users = (const int*)  d_in[5];
    const int*   pos   = (const int*)  d_in[6];
    const int*   neg   = (const int*)  d_in[7];
    float* out = (float*)d_out;

    char* ws = (char*)d_ws;
    const size_t tblB  = (size_t)150016 * EMB * sizeof(u16);       // 19.2 MB
    const size_t pairB = (size_t)NNZ_TOT * sizeof(int2);           // 38.4 MB
    u16*  ego0   = (u16*)(ws);
    u16*  ego1   = (u16*)(ws + tblB);
    int2* pairs  = (int2*)(ws + 2 * tblB);
    int*  rowptr = (int*) (ws + 2 * tblB + pairB);
    int*  deg    = rowptr + ((SCAN_N + 63) & ~63);
    int*  fill   = deg + N_NODES;

    const int blk = 256;

    // bf16 ego0
    const size_t n4 = (size_t)N_NODES * EMB / 4;
    k_init<<<(int)((n4 + blk - 1) / blk), blk, 0, stream>>>(ue, ie, ego0);

    // CSR build
    k_zero<<<(2 * N_NODES + blk - 1) / blk, blk, 0, stream>>>(deg, 2 * N_NODES);
    k_hist<<<(NNZ_TOT + blk - 1) / blk, blk, 0, stream>>>(erow, deg);
    k_scan<<<1, 1024, 0, stream>>>(deg, rowptr);
    k_fill<<<(NNZ_TOT + blk - 1) / blk, blk, 0, stream>>>(erow, ecol, eval_, rowptr, fill, pairs);

    // out = ego0 contribution (exact f32)
    const int grid_g = (int)(((size_t)3 * BATCH_SZ * 16 + blk - 1) / blk);
    k_out0<<<grid_g, blk, 0, stream>>>(ue, ie, users, pos, neg, out);

    // 3 propagation layers
    const size_t spmv_threads = (size_t)N_NODES * 64;
    const int grid_spmv = (int)((spmv_threads + blk - 1) / blk);
    u16* cur = ego0;
    u16* nxt = ego1;
    for (int layer = 0; layer < 3; ++layer) {
        k_spmv<<<grid_spmv, blk, 0, stream>>>(rowptr, pairs, cur, nxt);
        k_outb<<<grid_g, blk, 0, stream>>>(nxt, users, pos, neg, out,
                                           (layer == 2) ? 0.25f : 1.0f);
        u16* tmp = cur; cur = nxt; nxt = tmp;
    }
}

// Round 6
// 579.123 us; speedup vs baseline: 8.9029x; 2.0135x over previous
//
#include <hip/hip_runtime.h>

#define N_USERS 100000
#define N_ITEMS 50000
#define N_NODES 150000
#define EMB 64
#define NNZ_TOT 4800000
#define BATCH_SZ 4096

#define BROWS 64                  // rows per bucket
#define NB 2344                   // ceil(150000/64)
#define CHUNKS 256
#define CHUNKE 18750              // NNZ_TOT / CHUNKS (exact)
#define SBUF 3072                 // LDS sort buffer (bucket mean 2048, 22-sigma safe)

typedef unsigned short u16;

static __device__ __forceinline__ u16 f2bf(float f) {
    unsigned u = __float_as_uint(f);
    unsigned r = u + 0x7FFFu + ((u >> 16) & 1u);   // RNE
    return (u16)(r >> 16);
}
static __device__ __forceinline__ float bf2f(u16 h) {
    return __uint_as_float(((unsigned)h) << 16);
}

// ---------------- ego0 (bf16) = concat(user, item) ----------------
__global__ void k_init(const float* __restrict__ ue, const float* __restrict__ ie,
                       u16* __restrict__ ego) {
    size_t i = (size_t)blockIdx.x * blockDim.x + threadIdx.x;
    const size_t n4 = (size_t)N_NODES * EMB / 4;
    if (i >= n4) return;
    const size_t u4 = (size_t)N_USERS * EMB / 4;
    float4 v = (i < u4) ? ((const float4*)ue)[i] : ((const float4*)ie)[i - u4];
    ushort4 o;
    o.x = f2bf(v.x); o.y = f2bf(v.y); o.z = f2bf(v.z); o.w = f2bf(v.w);
    ((ushort4*)ego)[i] = o;
}

__global__ void k_zero(int* __restrict__ p, int n) {
    int i = blockIdx.x * blockDim.x + threadIdx.x;
    if (i < n) p[i] = 0;
}

// ---------------- per-chunk counting-sort into 64-row buckets (L2-hot writes) ----------------
__global__ __launch_bounds__(256) void k_bin(const int* __restrict__ erow,
                                             const int* __restrict__ ecol,
                                             const float* __restrict__ eval_,
                                             int2* __restrict__ pairsA,
                                             int* __restrict__ off_t,     // [(NB+1)][CHUNKS]
                                             int* __restrict__ bucketCnt) {
    __shared__ int hist[NB];
    __shared__ int fill[NB];
    const int c = blockIdx.x;
    const int cbase = c * CHUNKE;
    const int tid = threadIdx.x;

    for (int i = tid; i < NB; i += 256) hist[i] = 0;
    __syncthreads();

    for (int i = tid; i < CHUNKE; i += 256)
        atomicAdd(&hist[erow[cbase + i] >> 6], 1);
    __syncthreads();

    // exclusive scan of hist -> fill (wave 0)
    if (tid < 64) {
        int carry = 0;
        for (int blk = 0; blk < (NB + 63) / 64; ++blk) {
            int idx = blk * 64 + tid;
            int v = (idx < NB) ? hist[idx] : 0;
            int s = v;
            #pragma unroll
            for (int o = 1; o < 64; o <<= 1) {
                int t = __shfl_up(s, o);
                if (tid >= o) s += t;
            }
            if (idx < NB) fill[idx] = s - v + carry;
            carry += __shfl(s, 63);
        }
    }
    __syncthreads();

    // publish transposed segment starts + bucket totals
    for (int i = tid; i < NB; i += 256) {
        off_t[i * CHUNKS + c] = cbase + fill[i];
        atomicAdd(&bucketCnt[i], hist[i]);
    }
    if (tid == 0) off_t[NB * CHUNKS + c] = cbase + CHUNKE;
    __syncthreads();

    // scatter packed (row_local<<18 | col, val) into chunk-private region
    for (int i = tid; i < CHUNKE; i += 256) {
        int e = cbase + i;
        int r = erow[e];
        int bb = r >> 6;
        int p = atomicAdd(&fill[bb], 1);
        int2 pr;
        pr.x = ((r & 63) << 18) | ecol[e];
        pr.y = __float_as_int(eval_[e]);
        pairsA[cbase + p] = pr;
    }
}

// ---------------- scan bucket counts -> bucket_base[0..NB]; rowptr[N_NODES]=NNZ ----------------
__global__ __launch_bounds__(1024) void k_bscan(const int* __restrict__ cnt,
                                                int* __restrict__ bbase,
                                                int* __restrict__ rowptr) {
    __shared__ int lds[1024];
    const int tid = threadIdx.x;
    int vals[3];
    int local = 0;
    #pragma unroll
    for (int j = 0; j < 3; ++j) {
        int idx = tid * 3 + j;
        int v = (idx < NB) ? cnt[idx] : 0;
        vals[j] = local;
        local += v;
    }
    lds[tid] = local;
    __syncthreads();
    for (int off = 1; off < 1024; off <<= 1) {
        int t = (tid >= off) ? lds[tid - off] : 0;
        __syncthreads();
        lds[tid] += t;
        __syncthreads();
    }
    int excl = lds[tid] - local;
    #pragma unroll
    for (int j = 0; j < 3; ++j) {
        int idx = tid * 3 + j;
        if (idx <= NB) {
            int b = excl + vals[j];
            bbase[idx] = b;
            if (idx == NB) rowptr[N_NODES] = b;   // == NNZ_TOT
        }
    }
}

// ---------------- per-bucket LDS counting sort -> row-sorted CSR ----------------
__global__ __launch_bounds__(256) void k_sort(const int* __restrict__ off_t,
                                              const int2* __restrict__ pairsA,
                                              const int* __restrict__ bbase,
                                              int2* __restrict__ pairsB,
                                              int* __restrict__ rowptr) {
    __shared__ int hist[BROWS];
    __shared__ int fillx[BROWS];
    __shared__ int2 buf[SBUF];
    const int b = blockIdx.x;
    const int tid = threadIdx.x;

    const int s = off_t[b * CHUNKS + tid];
    const int e = off_t[(b + 1) * CHUNKS + tid];

    if (tid < BROWS) hist[tid] = 0;
    __syncthreads();

    for (int i = s; i < e; ++i)
        atomicAdd(&hist[(pairsA[i].x >> 18) & 63], 1);
    __syncthreads();

    const int base = bbase[b];
    if (tid < BROWS) {
        int v = hist[tid];
        int sc = v;
        #pragma unroll
        for (int o = 1; o < 64; o <<= 1) {
            int t = __shfl_up(sc, o);
            if (tid >= o) sc += t;
        }
        int excl = sc - v;
        fillx[tid] = excl;
        int node = b * BROWS + tid;
        if (node < N_NODES) rowptr[node] = base + excl;
    }
    __syncthreads();

    for (int i = s; i < e; ++i) {
        int2 p = pairsA[i];
        int rl = (p.x >> 18) & 63;
        int pos = atomicAdd(&fillx[rl], 1);
        if (pos < SBUF) buf[pos] = make_int2(p.x & 0x3FFFF, p.y);
    }
    __syncthreads();

    int total = bbase[b + 1] - base;
    if (total > SBUF) total = SBUF;
    for (int i = tid; i < total; i += 256)
        pairsB[base + i] = buf[i];
}

// ---------------- SpMV: one wave per row, lane = emb element, bf16 tables ----------------
__global__ __launch_bounds__(256) void k_spmv(const int* __restrict__ rowptr,
                                              const int2* __restrict__ pairs,
                                              const u16* __restrict__ cur,
                                              u16* __restrict__ nxt) {
    size_t gid = (size_t)blockIdx.x * blockDim.x + threadIdx.x;
    int row  = (int)(gid >> 6);
    int lane = (int)(gid & 63);
    if (row >= N_NODES) return;
    int start = rowptr[row];
    int end   = rowptr[row + 1];
    float a0 = 0.f, a1 = 0.f, a2 = 0.f, a3 = 0.f;
    int e = start;
    for (; e + 7 < end; e += 8) {
        int2 q0 = pairs[e],     q1 = pairs[e + 1], q2 = pairs[e + 2], q3 = pairs[e + 3];
        int2 q4 = pairs[e + 4], q5 = pairs[e + 5], q6 = pairs[e + 6], q7 = pairs[e + 7];
        int   c0 = __builtin_amdgcn_readfirstlane(q0.x);
        float v0 = __uint_as_float(__builtin_amdgcn_readfirstlane(q0.y));
        int   c1 = __builtin_amdgcn_readfirstlane(q1.x);
        float v1 = __uint_as_float(__builtin_amdgcn_readfirstlane(q1.y));
        int   c2 = __builtin_amdgcn_readfirstlane(q2.x);
        float v2 = __uint_as_float(__builtin_amdgcn_readfirstlane(q2.y));
        int   c3 = __builtin_amdgcn_readfirstlane(q3.x);
        float v3 = __uint_as_float(__builtin_amdgcn_readfirstlane(q3.y));
        int   c4 = __builtin_amdgcn_readfirstlane(q4.x);
        float v4 = __uint_as_float(__builtin_amdgcn_readfirstlane(q4.y));
        int   c5 = __builtin_amdgcn_readfirstlane(q5.x);
        float v5 = __uint_as_float(__builtin_amdgcn_readfirstlane(q5.y));
        int   c6 = __builtin_amdgcn_readfirstlane(q6.x);
        float v6 = __uint_as_float(__builtin_amdgcn_readfirstlane(q6.y));
        int   c7 = __builtin_amdgcn_readfirstlane(q7.x);
        float v7 = __uint_as_float(__builtin_amdgcn_readfirstlane(q7.y));
        a0 += v0 * bf2f(cur[(size_t)c0 * EMB + lane]);
        a1 += v1 * bf2f(cur[(size_t)c1 * EMB + lane]);
        a2 += v2 * bf2f(cur[(size_t)c2 * EMB + lane]);
        a3 += v3 * bf2f(cur[(size_t)c3 * EMB + lane]);
        a0 += v4 * bf2f(cur[(size_t)c4 * EMB + lane]);
        a1 += v5 * bf2f(cur[(size_t)c5 * EMB + lane]);
        a2 += v6 * bf2f(cur[(size_t)c6 * EMB + lane]);
        a3 += v7 * bf2f(cur[(size_t)c7 * EMB + lane]);
    }
    for (; e < end; ++e) {
        int2 q = pairs[e];
        int   c = __builtin_amdgcn_readfirstlane(q.x);
        float v = __uint_as_float(__builtin_amdgcn_readfirstlane(q.y));
        a0 += v * bf2f(cur[(size_t)c * EMB + lane]);
    }
    nxt[(size_t)row * EMB + lane] = f2bf((a0 + a1) + (a2 + a3));
}

// ---------------- out = layer-0 gather from f32 originals (exact) ----------------
__global__ void k_out0(const float* __restrict__ ue, const float* __restrict__ ie,
                       const int* __restrict__ users, const int* __restrict__ pos,
                       const int* __restrict__ neg, float* __restrict__ out) {
    size_t t = (size_t)blockIdx.x * blockDim.x + threadIdx.x;
    size_t r = t >> 4;
    int sub = (int)(t & 15);
    if (r >= (size_t)(3 * BATCH_SZ)) return;
    int which = (int)(r / BATCH_SZ);
    int bi    = (int)(r % BATCH_SZ);
    int node;
    if (which == 0)      node = users[bi];
    else if (which == 1) node = N_USERS + pos[bi];
    else                 node = N_USERS + neg[bi];
    const float* src = (node < N_USERS) ? (ue + (size_t)node * EMB)
                                        : (ie + (size_t)(node - N_USERS) * EMB);
    float4 v = ((const float4*)src)[sub];
    ((float4*)(out + r * EMB))[sub] = v;
}

// ---------------- out += layer-k gather (bf16) ----------------
__global__ void k_outb(const u16* __restrict__ ego,
                       const int* __restrict__ users, const int* __restrict__ pos,
                       const int* __restrict__ neg, float* __restrict__ out) {
    size_t t = (size_t)blockIdx.x * blockDim.x + threadIdx.x;
    size_t r = t >> 4;
    int sub = (int)(t & 15);
    if (r >= (size_t)(3 * BATCH_SZ)) return;
    int which = (int)(r / BATCH_SZ);
    int bi    = (int)(r % BATCH_SZ);
    int node;
    if (which == 0)      node = users[bi];
    else if (which == 1) node = N_USERS + pos[bi];
    else                 node = N_USERS + neg[bi];
    ushort4 h = ((const ushort4*)(ego + (size_t)node * EMB))[sub];
    float4* op = (float4*)(out + r * EMB) + sub;
    float4 o = *op;
    o.x += bf2f(h.x); o.y += bf2f(h.y); o.z += bf2f(h.z); o.w += bf2f(h.w);
    *op = o;
}

// ---------------- fused layer-3 spmv (batch rows only) + final scale ----------------
__global__ __launch_bounds__(256) void k_last(const int* __restrict__ rowptr,
                                              const int2* __restrict__ pairs,
                                              const u16* __restrict__ cur,
                                              const int* __restrict__ users,
                                              const int* __restrict__ pos,
                                              const int* __restrict__ neg,
                                              float* __restrict__ out) {
    size_t gid = (size_t)blockIdx.x * blockDim.x + threadIdx.x;
    int r    = (int)(gid >> 6);
    int lane = (int)(gid & 63);
    if (r >= 3 * BATCH_SZ) return;
    int which = r / BATCH_SZ;
    int bi    = r % BATCH_SZ;
    int node;
    if (which == 0)      node = users[bi];
    else if (which == 1) node = N_USERS + pos[bi];
    else                 node = N_USERS + neg[bi];
    int start = rowptr[node];
    int end   = rowptr[node + 1];
    float a0 = 0.f, a1 = 0.f, a2 = 0.f, a3 = 0.f;
    int e = start;
    for (; e + 3 < end; e += 4) {
        int2 q0 = pairs[e], q1 = pairs[e + 1], q2 = pairs[e + 2], q3 = pairs[e + 3];
        int   c0 = __builtin_amdgcn_readfirstlane(q0.x);
        float v0 = __uint_as_float(__builtin_amdgcn_readfirstlane(q0.y));
        int   c1 = __builtin_amdgcn_readfirstlane(q1.x);
        float v1 = __uint_as_float(__builtin_amdgcn_readfirstlane(q1.y));
        int   c2 = __builtin_amdgcn_readfirstlane(q2.x);
        float v2 = __uint_as_float(__builtin_amdgcn_readfirstlane(q2.y));
        int   c3 = __builtin_amdgcn_readfirstlane(q3.x);
        float v3 = __uint_as_float(__builtin_amdgcn_readfirstlane(q3.y));
        a0 += v0 * bf2f(cur[(size_t)c0 * EMB + lane]);
        a1 += v1 * bf2f(cur[(size_t)c1 * EMB + lane]);
        a2 += v2 * bf2f(cur[(size_t)c2 * EMB + lane]);
        a3 += v3 * bf2f(cur[(size_t)c3 * EMB + lane]);
    }
    for (; e < end; ++e) {
        int2 q = pairs[e];
        int   c = __builtin_amdgcn_readfirstlane(q.x);
        float v = __uint_as_float(__builtin_amdgcn_readfirstlane(q.y));
        a0 += v * bf2f(cur[(size_t)c * EMB + lane]);
    }
    float sum = (a0 + a1) + (a2 + a3);
    size_t oi = (size_t)r * EMB + lane;
    out[oi] = (out[oi] + sum) * 0.25f;
}

extern "C" void kernel_launch(void* const* d_in, const int* in_sizes, int n_in,
                              void* d_out, int out_size, void* d_ws, size_t ws_size,
                              hipStream_t stream) {
    const int*   erow  = (const int*)  d_in[0];
    const int*   ecol  = (const int*)  d_in[1];
    const float* eval_ = (const float*)d_in[2];
    const float* ue    = (const float*)d_in[3];
    const float* ie    = (const float*)d_in[4];
    const int*   users = (const int*)  d_in[5];
    const int*   pos   = (const int*)  d_in[6];
    const int*   neg   = (const int*)  d_in[7];
    float* out = (float*)d_out;

    char* ws = (char*)d_ws;
    const size_t tblB  = (size_t)150016 * EMB * sizeof(u16);       // 19,202,048 B
    const size_t pairB = (size_t)NNZ_TOT * sizeof(int2);           // 38,400,000 B
    // pairsA aliases [ego0|ego1] (2*tblB >= pairB); k_init runs AFTER k_sort.
    u16*  ego0   = (u16*)(ws);
    u16*  ego1   = (u16*)(ws + tblB);
    int2* pairsA = (int2*)(ws);
    int2* pairsB = (int2*)(ws + 2 * tblB);
    int*  off_t  = (int*) (ws + 2 * tblB + pairB);                 // (NB+1)*CHUNKS ints
    int*  rowptr = off_t + (size_t)(NB + 1) * CHUNKS;              // N_NODES+1 ints
    int*  bucketCnt = rowptr + ((N_NODES + 1 + 63) & ~63);         // NB ints
    int*  bbase     = bucketCnt + NB;                              // NB+1 ints

    const int blk = 256;

    // CSR build (uses ego region as scratch for pairsA)
    k_zero<<<(NB + blk - 1) / blk, blk, 0, stream>>>(bucketCnt, NB);
    k_bin<<<CHUNKS, blk, 0, stream>>>(erow, ecol, eval_, pairsA, off_t, bucketCnt);
    k_bscan<<<1, 1024, 0, stream>>>(bucketCnt, bbase, rowptr);
    k_sort<<<NB, blk, 0, stream>>>(off_t, pairsA, bbase, pairsB, rowptr);

    // bf16 ego0 (overwrites dead pairsA)
    const size_t n4 = (size_t)N_NODES * EMB / 4;
    k_init<<<(int)((n4 + blk - 1) / blk), blk, 0, stream>>>(ue, ie, ego0);

    // out = layer-0 contribution (exact f32)
    const int grid_g = (int)(((size_t)3 * BATCH_SZ * 16 + blk - 1) / blk);
    k_out0<<<grid_g, blk, 0, stream>>>(ue, ie, users, pos, neg, out);

    // layers 1,2 full propagation; layer 3 fused into output
    const size_t spmv_threads = (size_t)N_NODES * 64;
    const int grid_spmv = (int)((spmv_threads + blk - 1) / blk);
    k_spmv<<<grid_spmv, blk, 0, stream>>>(rowptr, pairsB, ego0, ego1);
    k_outb<<<grid_g, blk, 0, stream>>>(ego1, users, pos, neg, out);
    k_spmv<<<grid_spmv, blk, 0, stream>>>(rowptr, pairsB, ego1, ego0);
    k_outb<<<grid_g, blk, 0, stream>>>(ego0, users, pos, neg, out);

    const size_t lth = (size_t)3 * BATCH_SZ * 64;
    k_last<<<(int)((lth + blk - 1) / blk), blk, 0, stream>>>(rowptr, pairsB, ego0,
                                                             users, pos, neg, out);
}

// Round 7
// 543.771 us; speedup vs baseline: 9.4817x; 1.0650x over previous
//
#include <hip/hip_runtime.h>

#define N_USERS 100000
#define N_ITEMS 50000
#define N_NODES 150000
#define EMB 64
#define NNZ_TOT 4800000
#define BATCH_SZ 4096

#define BROWS 64                  // rows per bucket
#define NB 2344                   // ceil(150000/64)
#define CHUNKS 256
#define CHUNKE 18750              // NNZ_TOT / CHUNKS (exact)
#define SBUF 3072                 // LDS sort buffer (bucket mean 2048)

typedef unsigned short u16;

static __device__ __forceinline__ u16 f2bf(float f) {
    unsigned u = __float_as_uint(f);
    unsigned r = u + 0x7FFFu + ((u >> 16) & 1u);   // RNE
    return (u16)(r >> 16);
}
static __device__ __forceinline__ float bf2f(u16 h) {
    return __uint_as_float(((unsigned)h) << 16);
}

// ---------------- ego0 (bf16) = concat(user, item) ----------------
__global__ void k_init(const float* __restrict__ ue, const float* __restrict__ ie,
                       u16* __restrict__ ego) {
    size_t i = (size_t)blockIdx.x * blockDim.x + threadIdx.x;
    const size_t n4 = (size_t)N_NODES * EMB / 4;
    if (i >= n4) return;
    const size_t u4 = (size_t)N_USERS * EMB / 4;
    float4 v = (i < u4) ? ((const float4*)ue)[i] : ((const float4*)ie)[i - u4];
    ushort4 o;
    o.x = f2bf(v.x); o.y = f2bf(v.y); o.z = f2bf(v.z); o.w = f2bf(v.w);
    ((ushort4*)ego)[i] = o;
}

__global__ void k_zero(int* __restrict__ p, int n) {
    int i = blockIdx.x * blockDim.x + threadIdx.x;
    if (i < n) p[i] = 0;
}

// ---------------- per-chunk counting-sort into 64-row buckets (1024 thr) ----------------
__global__ __launch_bounds__(1024) void k_bin(const int* __restrict__ erow,
                                              const int* __restrict__ ecol,
                                              const float* __restrict__ eval_,
                                              int2* __restrict__ pairsA,
                                              int* __restrict__ off_t,     // [(NB+1)][CHUNKS]
                                              int* __restrict__ bucketCnt) {
    __shared__ int hist[NB];
    __shared__ int fill[NB];
    const int c = blockIdx.x;
    const int cbase = c * CHUNKE;
    const int tid = threadIdx.x;

    for (int i = tid; i < NB; i += 1024) hist[i] = 0;
    __syncthreads();

    for (int i = tid; i < CHUNKE; i += 1024)
        atomicAdd(&hist[erow[cbase + i] >> 6], 1);
    __syncthreads();

    // exclusive scan of hist -> fill (wave 0)
    if (tid < 64) {
        int carry = 0;
        for (int blk = 0; blk < (NB + 63) / 64; ++blk) {
            int idx = blk * 64 + tid;
            int v = (idx < NB) ? hist[idx] : 0;
            int s = v;
            #pragma unroll
            for (int o = 1; o < 64; o <<= 1) {
                int t = __shfl_up(s, o);
                if (tid >= o) s += t;
            }
            if (idx < NB) fill[idx] = s - v + carry;
            carry += __shfl(s, 63);
        }
    }
    __syncthreads();

    // publish transposed segment starts + bucket totals
    for (int i = tid; i < NB; i += 1024) {
        off_t[i * CHUNKS + c] = cbase + fill[i];
        atomicAdd(&bucketCnt[i], hist[i]);
    }
    if (tid == 0) off_t[NB * CHUNKS + c] = cbase + CHUNKE;
    __syncthreads();

    // scatter packed (row_local<<18 | col, val) into chunk-private region
    for (int i = tid; i < CHUNKE; i += 1024) {
        int e = cbase + i;
        int r = erow[e];
        int bb = r >> 6;
        int p = atomicAdd(&fill[bb], 1);
        int2 pr;
        pr.x = ((r & 63) << 18) | ecol[e];
        pr.y = __float_as_int(eval_[e]);
        pairsA[cbase + p] = pr;
    }
}

// ---------------- scan bucket counts -> bucket_base[0..NB]; rowptr[N_NODES]=NNZ ----------------
__global__ __launch_bounds__(1024) void k_bscan(const int* __restrict__ cnt,
                                                int* __restrict__ bbase,
                                                int* __restrict__ rowptr) {
    __shared__ int lds[1024];
    const int tid = threadIdx.x;
    int vals[3];
    int local = 0;
    #pragma unroll
    for (int j = 0; j < 3; ++j) {
        int idx = tid * 3 + j;
        int v = (idx < NB) ? cnt[idx] : 0;
        vals[j] = local;
        local += v;
    }
    lds[tid] = local;
    __syncthreads();
    for (int off = 1; off < 1024; off <<= 1) {
        int t = (tid >= off) ? lds[tid - off] : 0;
        __syncthreads();
        lds[tid] += t;
        __syncthreads();
    }
    int excl = lds[tid] - local;
    #pragma unroll
    for (int j = 0; j < 3; ++j) {
        int idx = tid * 3 + j;
        if (idx <= NB) {
            int b = excl + vals[j];
            bbase[idx] = b;
            if (idx == NB) rowptr[N_NODES] = b;   // == NNZ_TOT
        }
    }
}

// ---------------- per-bucket LDS counting sort -> row-sorted CSR ----------------
__global__ __launch_bounds__(256) void k_sort(const int* __restrict__ off_t,
                                              const int2* __restrict__ pairsA,
                                              const int* __restrict__ bbase,
                                              int2* __restrict__ pairsB,
                                              int* __restrict__ rowptr) {
    __shared__ int hist[BROWS];
    __shared__ int fillx[BROWS];
    __shared__ int2 buf[SBUF];
    const int b = blockIdx.x;
    const int tid = threadIdx.x;

    const int s = off_t[b * CHUNKS + tid];
    const int e = off_t[(b + 1) * CHUNKS + tid];

    if (tid < BROWS) hist[tid] = 0;
    __syncthreads();

    for (int i = s; i < e; ++i)
        atomicAdd(&hist[(pairsA[i].x >> 18) & 63], 1);
    __syncthreads();

    const int base = bbase[b];
    if (tid < BROWS) {
        int v = hist[tid];
        int sc = v;
        #pragma unroll
        for (int o = 1; o < 64; o <<= 1) {
            int t = __shfl_up(sc, o);
            if (tid >= o) sc += t;
        }
        int excl = sc - v;
        fillx[tid] = excl;
        int node = b * BROWS + tid;
        if (node < N_NODES) rowptr[node] = base + excl;
    }
    __syncthreads();

    for (int i = s; i < e; ++i) {
        int2 p = pairsA[i];
        int rl = (p.x >> 18) & 63;
        int pos = atomicAdd(&fillx[rl], 1);
        if (pos < SBUF) buf[pos] = make_int2(p.x & 0x3FFFF, p.y);
    }
    __syncthreads();

    int total = bbase[b + 1] - base;
    if (total > SBUF) total = SBUF;
    for (int i = tid; i < total; i += 256)
        pairsB[base + i] = buf[i];
}

// ---------------- SpMV: one wave per row, int4 pair loads, bf16 tables ----------------
__global__ __launch_bounds__(256) void k_spmv(const int* __restrict__ rowptr,
                                              const int2* __restrict__ pairs,
                                              const u16* __restrict__ cur,
                                              u16* __restrict__ nxt) {
    size_t gid = (size_t)blockIdx.x * blockDim.x + threadIdx.x;
    int row  = (int)(gid >> 6);
    int lane = (int)(gid & 63);
    if (row >= N_NODES) return;
    int start = rowptr[row];
    int end   = rowptr[row + 1];
    float a0 = 0.f, a1 = 0.f, a2 = 0.f, a3 = 0.f;
    int e = start;
    if ((e & 1) && e < end) {                       // align to int4 boundary
        int2 q = pairs[e];
        int   c = __builtin_amdgcn_readfirstlane(q.x);
        float v = __uint_as_float(__builtin_amdgcn_readfirstlane(q.y));
        a0 += v * bf2f(cur[(size_t)c * EMB + lane]);
        ++e;
    }
    const int4* p4 = (const int4*)pairs;
    for (; e + 7 < end; e += 8) {
        int4 d0 = p4[(e >> 1) + 0];
        int4 d1 = p4[(e >> 1) + 1];
        int4 d2 = p4[(e >> 1) + 2];
        int4 d3 = p4[(e >> 1) + 3];
        int   c0 = __builtin_amdgcn_readfirstlane(d0.x);
        float v0 = __uint_as_float(__builtin_amdgcn_readfirstlane(d0.y));
        int   c1 = __builtin_amdgcn_readfirstlane(d0.z);
        float v1 = __uint_as_float(__builtin_amdgcn_readfirstlane(d0.w));
        int   c2 = __builtin_amdgcn_readfirstlane(d1.x);
        float v2 = __uint_as_float(__builtin_amdgcn_readfirstlane(d1.y));
        int   c3 = __builtin_amdgcn_readfirstlane(d1.z);
        float v3 = __uint_as_float(__builtin_amdgcn_readfirstlane(d1.w));
        int   c4 = __builtin_amdgcn_readfirstlane(d2.x);
        float v4 = __uint_as_float(__builtin_amdgcn_readfirstlane(d2.y));
        int   c5 = __builtin_amdgcn_readfirstlane(d2.z);
        float v5 = __uint_as_float(__builtin_amdgcn_readfirstlane(d2.w));
        int   c6 = __builtin_amdgcn_readfirstlane(d3.x);
        float v6 = __uint_as_float(__builtin_amdgcn_readfirstlane(d3.y));
        int   c7 = __builtin_amdgcn_readfirstlane(d3.z);
        float v7 = __uint_as_float(__builtin_amdgcn_readfirstlane(d3.w));
        a0 += v0 * bf2f(cur[(size_t)c0 * EMB + lane]);
        a1 += v1 * bf2f(cur[(size_t)c1 * EMB + lane]);
        a2 += v2 * bf2f(cur[(size_t)c2 * EMB + lane]);
        a3 += v3 * bf2f(cur[(size_t)c3 * EMB + lane]);
        a0 += v4 * bf2f(cur[(size_t)c4 * EMB + lane]);
        a1 += v5 * bf2f(cur[(size_t)c5 * EMB + lane]);
        a2 += v6 * bf2f(cur[(size_t)c6 * EMB + lane]);
        a3 += v7 * bf2f(cur[(size_t)c7 * EMB + lane]);
    }
    for (; e < end; ++e) {
        int2 q = pairs[e];
        int   c = __builtin_amdgcn_readfirstlane(q.x);
        float v = __uint_as_float(__builtin_amdgcn_readfirstlane(q.y));
        a0 += v * bf2f(cur[(size_t)c * EMB + lane]);
    }
    nxt[(size_t)row * EMB + lane] = f2bf((a0 + a1) + (a2 + a3));
}

// ---------------- out = layer-0 gather from f32 originals (exact) ----------------
__global__ void k_out0(const float* __restrict__ ue, const float* __restrict__ ie,
                       const int* __restrict__ users, const int* __restrict__ pos,
                       const int* __restrict__ neg, float* __restrict__ out) {
    size_t t = (size_t)blockIdx.x * blockDim.x + threadIdx.x;
    size_t r = t >> 4;
    int sub = (int)(t & 15);
    if (r >= (size_t)(3 * BATCH_SZ)) return;
    int which = (int)(r / BATCH_SZ);
    int bi    = (int)(r % BATCH_SZ);
    int node;
    if (which == 0)      node = users[bi];
    else if (which == 1) node = N_USERS + pos[bi];
    else                 node = N_USERS + neg[bi];
    const float* src = (node < N_USERS) ? (ue + (size_t)node * EMB)
                                        : (ie + (size_t)(node - N_USERS) * EMB);
    float4 v = ((const float4*)src)[sub];
    ((float4*)(out + r * EMB))[sub] = v;
}

// ---------------- out += layer-k gather (bf16) ----------------
__global__ void k_outb(const u16* __restrict__ ego,
                       const int* __restrict__ users, const int* __restrict__ pos,
                       const int* __restrict__ neg, float* __restrict__ out) {
    size_t t = (size_t)blockIdx.x * blockDim.x + threadIdx.x;
    size_t r = t >> 4;
    int sub = (int)(t & 15);
    if (r >= (size_t)(3 * BATCH_SZ)) return;
    int which = (int)(r / BATCH_SZ);
    int bi    = (int)(r % BATCH_SZ);
    int node;
    if (which == 0)      node = users[bi];
    else if (which == 1) node = N_USERS + pos[bi];
    else                 node = N_USERS + neg[bi];
    ushort4 h = ((const ushort4*)(ego + (size_t)node * EMB))[sub];
    float4* op = (float4*)(out + r * EMB) + sub;
    float4 o = *op;
    o.x += bf2f(h.x); o.y += bf2f(h.y); o.z += bf2f(h.z); o.w += bf2f(h.w);
    *op = o;
}

// ---------------- fused layer-3 spmv (batch rows only) + final scale ----------------
__global__ __launch_bounds__(256) void k_last(const int* __restrict__ rowptr,
                                              const int2* __restrict__ pairs,
                                              const u16* __restrict__ cur,
                                              const int* __restrict__ users,
                                              const int* __restrict__ pos,
                                              const int* __restrict__ neg,
                                              float* __restrict__ out) {
    size_t gid = (size_t)blockIdx.x * blockDim.x + threadIdx.x;
    int r    = (int)(gid >> 6);
    int lane = (int)(gid & 63);
    if (r >= 3 * BATCH_SZ) return;
    int which = r / BATCH_SZ;
    int bi    = r % BATCH_SZ;
    int node;
    if (which == 0)      node = users[bi];
    else if (which == 1) node = N_USERS + pos[bi];
    else                 node = N_USERS + neg[bi];
    int start = rowptr[node];
    int end   = rowptr[node + 1];
    float a0 = 0.f, a1 = 0.f, a2 = 0.f, a3 = 0.f;
    int e = start;
    for (; e + 3 < end; e += 4) {
        int2 q0 = pairs[e], q1 = pairs[e + 1], q2 = pairs[e + 2], q3 = pairs[e + 3];
        int   c0 = __builtin_amdgcn_readfirstlane(q0.x);
        float v0 = __uint_as_float(__builtin_amdgcn_readfirstlane(q0.y));
        int   c1 = __builtin_amdgcn_readfirstlane(q1.x);
        float v1 = __uint_as_float(__builtin_amdgcn_readfirstlane(q1.y));
        int   c2 = __builtin_amdgcn_readfirstlane(q2.x);
        float v2 = __uint_as_float(__builtin_amdgcn_readfirstlane(q2.y));
        int   c3 = __builtin_amdgcn_readfirstlane(q3.x);
        float v3 = __uint_as_float(__builtin_amdgcn_readfirstlane(q3.y));
        a0 += v0 * bf2f(cur[(size_t)c0 * EMB + lane]);
        a1 += v1 * bf2f(cur[(size_t)c1 * EMB + lane]);
        a2 += v2 * bf2f(cur[(size_t)c2 * EMB + lane]);
        a3 += v3 * bf2f(cur[(size_t)c3 * EMB + lane]);
    }
    for (; e < end; ++e) {
        int2 q = pairs[e];
        int   c = __builtin_amdgcn_readfirstlane(q.x);
        float v = __uint_as_float(__builtin_amdgcn_readfirstlane(q.y));
        a0 += v * bf2f(cur[(size_t)c * EMB + lane]);
    }
    float sum = (a0 + a1) + (a2 + a3);
    size_t oi = (size_t)r * EMB + lane;
    out[oi] = (out[oi] + sum) * 0.25f;
}

extern "C" void kernel_launch(void* const* d_in, const int* in_sizes, int n_in,
                              void* d_out, int out_size, void* d_ws, size_t ws_size,
                              hipStream_t stream) {
    const int*   erow  = (const int*)  d_in[0];
    const int*   ecol  = (const int*)  d_in[1];
    const float* eval_ = (const float*)d_in[2];
    const float* ue    = (const float*)d_in[3];
    const float* ie    = (const float*)d_in[4];
    const int*   users = (const int*)  d_in[5];
    const int*   pos   = (const int*)  d_in[6];
    const int*   neg   = (const int*)  d_in[7];
    float* out = (float*)d_out;

    char* ws = (char*)d_ws;
    const size_t tblB  = (size_t)150016 * EMB * sizeof(u16);       // 19,202,048 B
    const size_t pairB = (size_t)NNZ_TOT * sizeof(int2);           // 38,400,000 B
    // pairsA aliases [ego0|ego1] (2*tblB >= pairB); k_init runs AFTER k_sort.
    u16*  ego0   = (u16*)(ws);
    u16*  ego1   = (u16*)(ws + tblB);
    int2* pairsA = (int2*)(ws);
    int2* pairsB = (int2*)(ws + 2 * tblB);
    int*  off_t  = (int*) (ws + 2 * tblB + pairB);                 // (NB+1)*CHUNKS ints
    int*  rowptr = off_t + (size_t)(NB + 1) * CHUNKS;              // N_NODES+1 ints
    int*  bucketCnt = rowptr + ((N_NODES + 1 + 63) & ~63);         // NB ints
    int*  bbase     = bucketCnt + NB;                              // NB+1 ints

    const int blk = 256;

    // CSR build (uses ego region as scratch for pairsA)
    k_zero<<<(NB + blk - 1) / blk, blk, 0, stream>>>(bucketCnt, NB);
    k_bin<<<CHUNKS, 1024, 0, stream>>>(erow, ecol, eval_, pairsA, off_t, bucketCnt);
    k_bscan<<<1, 1024, 0, stream>>>(bucketCnt, bbase, rowptr);
    k_sort<<<NB, blk, 0, stream>>>(off_t, pairsA, bbase, pairsB, rowptr);

    // bf16 ego0 (overwrites dead pairsA)
    const size_t n4 = (size_t)N_NODES * EMB / 4;
    k_init<<<(int)((n4 + blk - 1) / blk), blk, 0, stream>>>(ue, ie, ego0);

    // out = layer-0 contribution (exact f32)
    const int grid_g = (int)(((size_t)3 * BATCH_SZ * 16 + blk - 1) / blk);
    k_out0<<<grid_g, blk, 0, stream>>>(ue, ie, users, pos, neg, out);

    // layers 1,2 full propagation; layer 3 fused into output
    const size_t spmv_threads = (size_t)N_NODES * 64;
    const int grid_spmv = (int)((spmv_threads + blk - 1) / blk);
    k_spmv<<<grid_spmv, blk, 0, stream>>>(rowptr, pairsB, ego0, ego1);
    k_outb<<<grid_g, blk, 0, stream>>>(ego1, users, pos, neg, out);
    k_spmv<<<grid_spmv, blk, 0, stream>>>(rowptr, pairsB, ego1, ego0);
    k_outb<<<grid_g, blk, 0, stream>>>(ego0, users, pos, neg, out);

    const size_t lth = (size_t)3 * BATCH_SZ * 64;
    k_last<<<(int)((lth + blk - 1) / blk), blk, 0, stream>>>(rowptr, pairsB, ego0,
                                                             users, pos, neg, out);
}

// Round 8
// 521.054 us; speedup vs baseline: 9.8951x; 1.0436x over previous
//
#include <hip/hip_runtime.h>

#define N_USERS 100000
#define N_ITEMS 50000
#define N_NODES 150000
#define EMB 64
#define NNZ_TOT 4800000
#define BATCH_SZ 4096

#define BROWS 64                  // rows per bucket
#define NB 2344                   // ceil(150000/64)
#define CHUNKS 256
#define CHUNKE 18750              // NNZ_TOT / CHUNKS (exact)
#define SBUF 3072                 // LDS sort buffer (bucket mean 2048, ~22 sigma)
#define KBINS 2048                // sort key bins: row_local(6b) x col-tile(5b)

typedef unsigned short u16;

static __device__ __forceinline__ u16 f2bf(float f) {
    unsigned u = __float_as_uint(f);
    unsigned r = u + 0x7FFFu + ((u >> 16) & 1u);   // RNE
    return (u16)(r >> 16);
}
static __device__ __forceinline__ float bf2f(u16 h) {
    return __uint_as_float(((unsigned)h) << 16);
}

// ---------------- ego0 (bf16) = concat(user, item) ----------------
__global__ void k_init(const float* __restrict__ ue, const float* __restrict__ ie,
                       u16* __restrict__ ego) {
    size_t i = (size_t)blockIdx.x * blockDim.x + threadIdx.x;
    const size_t n4 = (size_t)N_NODES * EMB / 4;
    if (i >= n4) return;
    const size_t u4 = (size_t)N_USERS * EMB / 4;
    float4 v = (i < u4) ? ((const float4*)ue)[i] : ((const float4*)ie)[i - u4];
    ushort4 o;
    o.x = f2bf(v.x); o.y = f2bf(v.y); o.z = f2bf(v.z); o.w = f2bf(v.w);
    ((ushort4*)ego)[i] = o;
}

__global__ void k_zero(int* __restrict__ p, int n) {
    int i = blockIdx.x * blockDim.x + threadIdx.x;
    if (i < n) p[i] = 0;
}

// ---------------- per-chunk counting-sort into 64-row buckets (1024 thr) ----------------
__global__ __launch_bounds__(1024) void k_bin(const int* __restrict__ erow,
                                              const int* __restrict__ ecol,
                                              const float* __restrict__ eval_,
                                              int2* __restrict__ pairsA,
                                              int* __restrict__ off_t,     // [(NB+1)][CHUNKS]
                                              int* __restrict__ bucketCnt) {
    __shared__ int hist[NB];
    __shared__ int fill[NB];
    const int c = blockIdx.x;
    const int cbase = c * CHUNKE;
    const int tid = threadIdx.x;

    for (int i = tid; i < NB; i += 1024) hist[i] = 0;
    __syncthreads();

    for (int i = tid; i < CHUNKE; i += 1024)
        atomicAdd(&hist[erow[cbase + i] >> 6], 1);
    __syncthreads();

    // exclusive scan of hist -> fill (wave 0)
    if (tid < 64) {
        int carry = 0;
        for (int blk = 0; blk < (NB + 63) / 64; ++blk) {
            int idx = blk * 64 + tid;
            int v = (idx < NB) ? hist[idx] : 0;
            int s = v;
            #pragma unroll
            for (int o = 1; o < 64; o <<= 1) {
                int t = __shfl_up(s, o);
                if (tid >= o) s += t;
            }
            if (idx < NB) fill[idx] = s - v + carry;
            carry += __shfl(s, 63);
        }
    }
    __syncthreads();

    // publish transposed segment starts + bucket totals
    for (int i = tid; i < NB; i += 1024) {
        off_t[i * CHUNKS + c] = cbase + fill[i];
        atomicAdd(&bucketCnt[i], hist[i]);
    }
    if (tid == 0) off_t[NB * CHUNKS + c] = cbase + CHUNKE;
    __syncthreads();

    // scatter packed (row_local<<18 | col, val) into chunk-private region
    for (int i = tid; i < CHUNKE; i += 1024) {
        int e = cbase + i;
        int r = erow[e];
        int bb = r >> 6;
        int p = atomicAdd(&fill[bb], 1);
        int2 pr;
        pr.x = ((r & 63) << 18) | ecol[e];
        pr.y = __float_as_int(eval_[e]);
        pairsA[cbase + p] = pr;
    }
}

// ---------------- scan bucket counts -> bucket_base[0..NB]; rowptr[N_NODES]=NNZ ----------------
__global__ __launch_bounds__(1024) void k_bscan(const int* __restrict__ cnt,
                                                int* __restrict__ bbase,
                                                int* __restrict__ rowptr) {
    __shared__ int lds[1024];
    const int tid = threadIdx.x;
    int vals[3];
    int local = 0;
    #pragma unroll
    for (int j = 0; j < 3; ++j) {
        int idx = tid * 3 + j;
        int v = (idx < NB) ? cnt[idx] : 0;
        vals[j] = local;
        local += v;
    }
    lds[tid] = local;
    __syncthreads();
    for (int off = 1; off < 1024; off <<= 1) {
        int t = (tid >= off) ? lds[tid - off] : 0;
        __syncthreads();
        lds[tid] += t;
        __syncthreads();
    }
    int excl = lds[tid] - local;
    #pragma unroll
    for (int j = 0; j < 3; ++j) {
        int idx = tid * 3 + j;
        if (idx <= NB) {
            int b = excl + vals[j];
            bbase[idx] = b;
            if (idx == NB) rowptr[N_NODES] = b;   // == NNZ_TOT
        }
    }
}

// ---- per-bucket LDS sort by (row_local, col-tile) -> CSR with col-tiled rows ----
__global__ __launch_bounds__(256) void k_sort(const int* __restrict__ off_t,
                                              const int2* __restrict__ pairsA,
                                              const int* __restrict__ bbase,
                                              int2* __restrict__ pairsB,
                                              int* __restrict__ rowptr) {
    __shared__ int hist[KBINS];
    __shared__ int fillx[KBINS];
    __shared__ int2 buf[SBUF];
    __shared__ int wsum[4];
    const int b = blockIdx.x;
    const int tid = threadIdx.x, lane = tid & 63, w = tid >> 6;

    const int s = off_t[b * CHUNKS + tid];
    const int e = off_t[(b + 1) * CHUNKS + tid];
    const int len = e - s;

    for (int i = tid; i < KBINS; i += 256) hist[i] = 0;

    // block exclusive scan of segment lengths -> staging base per thread
    int sc = len;
    #pragma unroll
    for (int o = 1; o < 64; o <<= 1) {
        int t = __shfl_up(sc, o);
        if (lane >= o) sc += t;
    }
    if (lane == 63) wsum[w] = sc;
    __syncthreads();
    int wbase = 0;
    for (int i = 0; i < w; ++i) wbase += wsum[i];
    int tbase = wbase + sc - len;

    // stage into LDS (single global read of pairsA) + key histogram
    for (int i = 0; i < len; ++i) {
        int2 p = pairsA[s + i];
        int dst = tbase + i;
        if (dst < SBUF) buf[dst] = p;
        atomicAdd(&hist[(p.x >> 13) & (KBINS - 1)], 1);
    }
    __syncthreads();

    // scan KBINS bins (wave 0); emit rowptr at each row's first bin
    const int base = bbase[b];
    if (tid < 64) {
        int carry = 0;
        for (int blk = 0; blk < KBINS / 64; ++blk) {
            int idx = blk * 64 + tid;
            int v = hist[idx];
            int s2 = v;
            #pragma unroll
            for (int o = 1; o < 64; o <<= 1) {
                int t = __shfl_up(s2, o);
                if (tid >= o) s2 += t;
            }
            int excl = s2 - v + carry;
            fillx[idx] = excl;
            if ((idx & 31) == 0) {
                int node = b * BROWS + (idx >> 5);
                if (node < N_NODES) rowptr[node] = base + excl;
            }
            carry += __shfl(s2, 63);
        }
    }
    __syncthreads();

    // scatter staged edges to pairsB (bucket-local 16 KB window, L2-hot)
    int total = bbase[b + 1] - base;
    if (total > SBUF) total = SBUF;
    for (int i = tid; i < total; i += 256) {
        int2 p = buf[i];
        int pos = atomicAdd(&fillx[(p.x >> 13) & (KBINS - 1)], 1);
        pairsB[base + pos] = make_int2(p.x & 0x3FFFF, p.y);
    }
}

// ---------------- SpMV: one wave per row, int4 pair loads, bf16 tables ----------------
__global__ __launch_bounds__(256) void k_spmv(const int* __restrict__ rowptr,
                                              const int2* __restrict__ pairs,
                                              const u16* __restrict__ cur,
                                              u16* __restrict__ nxt) {
    size_t gid = (size_t)blockIdx.x * blockDim.x + threadIdx.x;
    int row  = (int)(gid >> 6);
    int lane = (int)(gid & 63);
    if (row >= N_NODES) return;
    int start = rowptr[row];
    int end   = rowptr[row + 1];
    float a0 = 0.f, a1 = 0.f, a2 = 0.f, a3 = 0.f;
    int e = start;
    if ((e & 1) && e < end) {                       // align to int4 boundary
        int2 q = pairs[e];
        int   c = __builtin_amdgcn_readfirstlane(q.x);
        float v = __uint_as_float(__builtin_amdgcn_readfirstlane(q.y));
        a0 += v * bf2f(cur[(size_t)c * EMB + lane]);
        ++e;
    }
    const int4* p4 = (const int4*)pairs;
    for (; e + 7 < end; e += 8) {
        int4 d0 = p4[(e >> 1) + 0];
        int4 d1 = p4[(e >> 1) + 1];
        int4 d2 = p4[(e >> 1) + 2];
        int4 d3 = p4[(e >> 1) + 3];
        int   c0 = __builtin_amdgcn_readfirstlane(d0.x);
        float v0 = __uint_as_float(__builtin_amdgcn_readfirstlane(d0.y));
        int   c1 = __builtin_amdgcn_readfirstlane(d0.z);
        float v1 = __uint_as_float(__builtin_amdgcn_readfirstlane(d0.w));
        int   c2 = __builtin_amdgcn_readfirstlane(d1.x);
        float v2 = __uint_as_float(__builtin_amdgcn_readfirstlane(d1.y));
        int   c3 = __builtin_amdgcn_readfirstlane(d1.z);
        float v3 = __uint_as_float(__builtin_amdgcn_readfirstlane(d1.w));
        int   c4 = __builtin_amdgcn_readfirstlane(d2.x);
        float v4 = __uint_as_float(__builtin_amdgcn_readfirstlane(d2.y));
        int   c5 = __builtin_amdgcn_readfirstlane(d2.z);
        float v5 = __uint_as_float(__builtin_amdgcn_readfirstlane(d2.w));
        int   c6 = __builtin_amdgcn_readfirstlane(d3.x);
        float v6 = __uint_as_float(__builtin_amdgcn_readfirstlane(d3.y));
        int   c7 = __builtin_amdgcn_readfirstlane(d3.z);
        float v7 = __uint_as_float(__builtin_amdgcn_readfirstlane(d3.w));
        a0 += v0 * bf2f(cur[(size_t)c0 * EMB + lane]);
        a1 += v1 * bf2f(cur[(size_t)c1 * EMB + lane]);
        a2 += v2 * bf2f(cur[(size_t)c2 * EMB + lane]);
        a3 += v3 * bf2f(cur[(size_t)c3 * EMB + lane]);
        a0 += v4 * bf2f(cur[(size_t)c4 * EMB + lane]);
        a1 += v5 * bf2f(cur[(size_t)c5 * EMB + lane]);
        a2 += v6 * bf2f(cur[(size_t)c6 * EMB + lane]);
        a3 += v7 * bf2f(cur[(size_t)c7 * EMB + lane]);
    }
    for (; e < end; ++e) {
        int2 q = pairs[e];
        int   c = __builtin_amdgcn_readfirstlane(q.x);
        float v = __uint_as_float(__builtin_amdgcn_readfirstlane(q.y));
        a0 += v * bf2f(cur[(size_t)c * EMB + lane]);
    }
    nxt[(size_t)row * EMB + lane] = f2bf((a0 + a1) + (a2 + a3));
}

// ---------------- out = layer-0 gather from f32 originals (exact) ----------------
__global__ void k_out0(const float* __restrict__ ue, const float* __restrict__ ie,
                       const int* __restrict__ users, const int* __restrict__ pos,
                       const int* __restrict__ neg, float* __restrict__ out) {
    size_t t = (size_t)blockIdx.x * blockDim.x + threadIdx.x;
    size_t r = t >> 4;
    int sub = (int)(t & 15);
    if (r >= (size_t)(3 * BATCH_SZ)) return;
    int which = (int)(r / BATCH_SZ);
    int bi    = (int)(r % BATCH_SZ);
    int node;
    if (which == 0)      node = users[bi];
    else if (which == 1) node = N_USERS + pos[bi];
    else                 node = N_USERS + neg[bi];
    const float* src = (node < N_USERS) ? (ue + (size_t)node * EMB)
                                        : (ie + (size_t)(node - N_USERS) * EMB);
    float4 v = ((const float4*)src)[sub];
    ((float4*)(out + r * EMB))[sub] = v;
}

// ---------------- out += layer-k gather (bf16) ----------------
__global__ void k_outb(const u16* __restrict__ ego,
                       const int* __restrict__ users, const int* __restrict__ pos,
                       const int* __restrict__ neg, float* __restrict__ out) {
    size_t t = (size_t)blockIdx.x * blockDim.x + threadIdx.x;
    size_t r = t >> 4;
    int sub = (int)(t & 15);
    if (r >= (size_t)(3 * BATCH_SZ)) return;
    int which = (int)(r / BATCH_SZ);
    int bi    = (int)(r % BATCH_SZ);
    int node;
    if (which == 0)      node = users[bi];
    else if (which == 1) node = N_USERS + pos[bi];
    else                 node = N_USERS + neg[bi];
    ushort4 h = ((const ushort4*)(ego + (size_t)node * EMB))[sub];
    float4* op = (float4*)(out + r * EMB) + sub;
    float4 o = *op;
    o.x += bf2f(h.x); o.y += bf2f(h.y); o.z += bf2f(h.z); o.w += bf2f(h.w);
    *op = o;
}

// ---------------- fused layer-3 spmv (batch rows only) + final scale ----------------
__global__ __launch_bounds__(256) void k_last(const int* __restrict__ rowptr,
                                              const int2* __restrict__ pairs,
                                              const u16* __restrict__ cur,
                                              const int* __restrict__ users,
                                              const int* __restrict__ pos,
                                              const int* __restrict__ neg,
                                              float* __restrict__ out) {
    size_t gid = (size_t)blockIdx.x * blockDim.x + threadIdx.x;
    int r    = (int)(gid >> 6);
    int lane = (int)(gid & 63);
    if (r >= 3 * BATCH_SZ) return;
    int which = r / BATCH_SZ;
    int bi    = r % BATCH_SZ;
    int node;
    if (which == 0)      node = users[bi];
    else if (which == 1) node = N_USERS + pos[bi];
    else                 node = N_USERS + neg[bi];
    int start = rowptr[node];
    int end   = rowptr[node + 1];
    float a0 = 0.f, a1 = 0.f, a2 = 0.f, a3 = 0.f;
    int e = start;
    for (; e + 3 < end; e += 4) {
        int2 q0 = pairs[e], q1 = pairs[e + 1], q2 = pairs[e + 2], q3 = pairs[e + 3];
        int   c0 = __builtin_amdgcn_readfirstlane(q0.x);
        float v0 = __uint_as_float(__builtin_amdgcn_readfirstlane(q0.y));
        int   c1 = __builtin_amdgcn_readfirstlane(q1.x);
        float v1 = __uint_as_float(__builtin_amdgcn_readfirstlane(q1.y));
        int   c2 = __builtin_amdgcn_readfirstlane(q2.x);
        float v2 = __uint_as_float(__builtin_amdgcn_readfirstlane(q2.y));
        int   c3 = __builtin_amdgcn_readfirstlane(q3.x);
        float v3 = __uint_as_float(__builtin_amdgcn_readfirstlane(q3.y));
        a0 += v0 * bf2f(cur[(size_t)c0 * EMB + lane]);
        a1 += v1 * bf2f(cur[(size_t)c1 * EMB + lane]);
        a2 += v2 * bf2f(cur[(size_t)c2 * EMB + lane]);
        a3 += v3 * bf2f(cur[(size_t)c3 * EMB + lane]);
    }
    for (; e < end; ++e) {
        int2 q = pairs[e];
        int   c = __builtin_amdgcn_readfirstlane(q.x);
        float v = __uint_as_float(__builtin_amdgcn_readfirstlane(q.y));
        a0 += v * bf2f(cur[(size_t)c * EMB + lane]);
    }
    float sum = (a0 + a1) + (a2 + a3);
    size_t oi = (size_t)r * EMB + lane;
    out[oi] = (out[oi] + sum) * 0.25f;
}

extern "C" void kernel_launch(void* const* d_in, const int* in_sizes, int n_in,
                              void* d_out, int out_size, void* d_ws, size_t ws_size,
                              hipStream_t stream) {
    const int*   erow  = (const int*)  d_in[0];
    const int*   ecol  = (const int*)  d_in[1];
    const float* eval_ = (const float*)d_in[2];
    const float* ue    = (const float*)d_in[3];
    const float* ie    = (const float*)d_in[4];
    const int*   users = (const int*)  d_in[5];
    const int*   pos   = (const int*)  d_in[6];
    const int*   neg   = (const int*)  d_in[7];
    float* out = (float*)d_out;

    char* ws = (char*)d_ws;
    const size_t tblB  = (size_t)150016 * EMB * sizeof(u16);       // 19,202,048 B
    const size_t pairB = (size_t)NNZ_TOT * sizeof(int2);           // 38,400,000 B
    // pairsA aliases [ego0|ego1] (2*tblB >= pairB); k_init runs AFTER k_sort.
    u16*  ego0   = (u16*)(ws);
    u16*  ego1   = (u16*)(ws + tblB);
    int2* pairsA = (int2*)(ws);
    int2* pairsB = (int2*)(ws + 2 * tblB);
    int*  off_t  = (int*) (ws + 2 * tblB + pairB);                 // (NB+1)*CHUNKS ints
    int*  rowptr = off_t + (size_t)(NB + 1) * CHUNKS;              // N_NODES+1 ints
    int*  bucketCnt = rowptr + ((N_NODES + 1 + 63) & ~63);         // NB ints
    int*  bbase     = bucketCnt + NB;                              // NB+1 ints

    const int blk = 256;

    // CSR build (uses ego region as scratch for pairsA)
    k_zero<<<(NB + blk - 1) / blk, blk, 0, stream>>>(bucketCnt, NB);
    k_bin<<<CHUNKS, 1024, 0, stream>>>(erow, ecol, eval_, pairsA, off_t, bucketCnt);
    k_bscan<<<1, 1024, 0, stream>>>(bucketCnt, bbase, rowptr);
    k_sort<<<NB, blk, 0, stream>>>(off_t, pairsA, bbase, pairsB, rowptr);

    // bf16 ego0 (overwrites dead pairsA)
    const size_t n4 = (size_t)N_NODES * EMB / 4;
    k_init<<<(int)((n4 + blk - 1) / blk), blk, 0, stream>>>(ue, ie, ego0);

    // out = layer-0 contribution (exact f32)
    const int grid_g = (int)(((size_t)3 * BATCH_SZ * 16 + blk - 1) / blk);
    k_out0<<<grid_g, blk, 0, stream>>>(ue, ie, users, pos, neg, out);

    // layers 1,2 full propagation; layer 3 fused into output
    const size_t spmv_threads = (size_t)N_NODES * 64;
    const int grid_spmv = (int)((spmv_threads + blk - 1) / blk);
    k_spmv<<<grid_spmv, blk, 0, stream>>>(rowptr, pairsB, ego0, ego1);
    k_outb<<<grid_g, blk, 0, stream>>>(ego1, users, pos, neg, out);
    k_spmv<<<grid_spmv, blk, 0, stream>>>(rowptr, pairsB, ego1, ego0);
    k_outb<<<grid_g, blk, 0, stream>>>(ego0, users, pos, neg, out);

    const size_t lth = (size_t)3 * BATCH_SZ * 64;
    k_last<<<(int)((lth + blk - 1) / blk), blk, 0, stream>>>(rowptr, pairsB, ego0,
                                                             users, pos, neg, out);
}

// Round 9
// 493.651 us; speedup vs baseline: 10.4444x; 1.0555x over previous
//
#include <hip/hip_runtime.h>

#define N_USERS 100000
#define N_ITEMS 50000
#define N_NODES 150000
#define EMB 64
#define NNZ_TOT 4800000
#define BATCH_SZ 4096

#define BROWS 64                  // rows per bucket
#define NB 2344                   // ceil(150000/64)
#define CHUNKS 256
#define CHUNKE 18750              // NNZ_TOT / CHUNKS (exact)
#define SBUF 3072                 // LDS sort buffer (bucket mean 2048, ~22 sigma)
#define KBINS 2048                // sort key bins

typedef unsigned short u16;

static __device__ __forceinline__ u16 f2bf(float f) {
    unsigned u = __float_as_uint(f);
    unsigned r = u + 0x7FFFu + ((u >> 16) & 1u);   // RNE
    return (u16)(r >> 16);
}
static __device__ __forceinline__ float bf2f(u16 h) {
    return __uint_as_float(((unsigned)h) << 16);
}

// ---------------- ego0 (bf16) = concat(user, item) ----------------
__global__ void k_init(const float* __restrict__ ue, const float* __restrict__ ie,
                       u16* __restrict__ ego) {
    size_t i = (size_t)blockIdx.x * blockDim.x + threadIdx.x;
    const size_t n4 = (size_t)N_NODES * EMB / 4;
    if (i >= n4) return;
    const size_t u4 = (size_t)N_USERS * EMB / 4;
    float4 v = (i < u4) ? ((const float4*)ue)[i] : ((const float4*)ie)[i - u4];
    ushort4 o;
    o.x = f2bf(v.x); o.y = f2bf(v.y); o.z = f2bf(v.z); o.w = f2bf(v.w);
    ((ushort4*)ego)[i] = o;
}

__global__ void k_zero(int* __restrict__ p, int n) {
    int i = blockIdx.x * blockDim.x + threadIdx.x;
    if (i < n) p[i] = 0;
}

// ---------------- per-chunk counting-sort into 64-row buckets (1024 thr) ----------------
__global__ __launch_bounds__(1024) void k_bin(const int* __restrict__ erow,
                                              const int* __restrict__ ecol,
                                              const float* __restrict__ eval_,
                                              int2* __restrict__ pairsA,
                                              int* __restrict__ off_t,     // [(NB+1)][CHUNKS]
                                              int* __restrict__ bucketCnt) {
    __shared__ int hist[NB];
    __shared__ int fill[NB];
    const int c = blockIdx.x;
    const int cbase = c * CHUNKE;
    const int tid = threadIdx.x;

    for (int i = tid; i < NB; i += 1024) hist[i] = 0;
    __syncthreads();

    for (int i = tid; i < CHUNKE; i += 1024)
        atomicAdd(&hist[erow[cbase + i] >> 6], 1);
    __syncthreads();

    // exclusive scan of hist -> fill (wave 0)
    if (tid < 64) {
        int carry = 0;
        for (int blk = 0; blk < (NB + 63) / 64; ++blk) {
            int idx = blk * 64 + tid;
            int v = (idx < NB) ? hist[idx] : 0;
            int s = v;
            #pragma unroll
            for (int o = 1; o < 64; o <<= 1) {
                int t = __shfl_up(s, o);
                if (tid >= o) s += t;
            }
            if (idx < NB) fill[idx] = s - v + carry;
            carry += __shfl(s, 63);
        }
    }
    __syncthreads();

    for (int i = tid; i < NB; i += 1024) {
        off_t[i * CHUNKS + c] = cbase + fill[i];
        atomicAdd(&bucketCnt[i], hist[i]);
    }
    if (tid == 0) off_t[NB * CHUNKS + c] = cbase + CHUNKE;
    __syncthreads();

    for (int i = tid; i < CHUNKE; i += 1024) {
        int e = cbase + i;
        int r = erow[e];
        int bb = r >> 6;
        int p = atomicAdd(&fill[bb], 1);
        int2 pr;
        pr.x = ((r & 63) << 18) | ecol[e];
        pr.y = __float_as_int(eval_[e]);
        pairsA[cbase + p] = pr;
    }
}

// ---------------- scan bucket counts -> bucket_base[0..NB] ----------------
__global__ __launch_bounds__(1024) void k_bscan(const int* __restrict__ cnt,
                                                int* __restrict__ bbase,
                                                int* __restrict__ rowptr) {
    __shared__ int lds[1024];
    const int tid = threadIdx.x;
    int vals[3];
    int local = 0;
    #pragma unroll
    for (int j = 0; j < 3; ++j) {
        int idx = tid * 3 + j;
        int v = (idx < NB) ? cnt[idx] : 0;
        vals[j] = local;
        local += v;
    }
    lds[tid] = local;
    __syncthreads();
    for (int off = 1; off < 1024; off <<= 1) {
        int t = (tid >= off) ? lds[tid - off] : 0;
        __syncthreads();
        lds[tid] += t;
        __syncthreads();
    }
    int excl = lds[tid] - local;
    #pragma unroll
    for (int j = 0; j < 3; ++j) {
        int idx = tid * 3 + j;
        if (idx <= NB) {
            int b = excl + vals[j];
            bbase[idx] = b;
            if (idx == NB) rowptr[N_NODES] = b;   // == NNZ_TOT
        }
    }
}

// ---- per-bucket LDS sort by (row_local, col-tile) -> row-sorted CSR ----
__global__ __launch_bounds__(256) void k_sort(const int* __restrict__ off_t,
                                              const int2* __restrict__ pairsA,
                                              const int* __restrict__ bbase,
                                              int2* __restrict__ pairsB,
                                              int* __restrict__ rowptr) {
    __shared__ int hist[KBINS];
    __shared__ int fillx[KBINS];
    __shared__ int2 buf[SBUF];
    __shared__ int wsum[4];
    const int b = blockIdx.x;
    const int tid = threadIdx.x, lane = tid & 63, w = tid >> 6;

    const int s = off_t[b * CHUNKS + tid];
    const int e = off_t[(b + 1) * CHUNKS + tid];
    const int len = e - s;

    for (int i = tid; i < KBINS; i += 256) hist[i] = 0;

    int sc = len;
    #pragma unroll
    for (int o = 1; o < 64; o <<= 1) {
        int t = __shfl_up(sc, o);
        if (lane >= o) sc += t;
    }
    if (lane == 63) wsum[w] = sc;
    __syncthreads();
    int wbase = 0;
    for (int i = 0; i < w; ++i) wbase += wsum[i];
    int tbase = wbase + sc - len;

    for (int i = 0; i < len; ++i) {
        int2 p = pairsA[s + i];
        int dst = tbase + i;
        if (dst < SBUF) buf[dst] = p;
        atomicAdd(&hist[(p.x >> 13) & (KBINS - 1)], 1);
    }
    __syncthreads();

    const int base = bbase[b];
    if (tid < 64) {
        int carry = 0;
        for (int blk = 0; blk < KBINS / 64; ++blk) {
            int idx = blk * 64 + tid;
            int v = hist[idx];
            int s2 = v;
            #pragma unroll
            for (int o = 1; o < 64; o <<= 1) {
                int t = __shfl_up(s2, o);
                if (tid >= o) s2 += t;
            }
            int excl = s2 - v + carry;
            fillx[idx] = excl;
            if ((idx & 31) == 0) {
                int node = b * BROWS + (idx >> 5);
                if (node < N_NODES) rowptr[node] = base + excl;
            }
            carry += __shfl(s2, 63);
        }
    }
    __syncthreads();

    int total = bbase[b + 1] - base;
    if (total > SBUF) total = SBUF;
    for (int i = tid; i < total; i += 256) {
        int2 p = buf[i];
        int pos = atomicAdd(&fillx[(p.x >> 13) & (KBINS - 1)], 1);
        pairsB[base + pos] = make_int2(p.x & 0x3FFFF, p.y);
    }
}

// ---- SpMV: wave per row; 2 edges per wave-gather (dword lanes); 16 edges/iter ----
#define RFL(x) __builtin_amdgcn_readfirstlane(x)
__global__ __launch_bounds__(256) void k_spmv(const int* __restrict__ rowptr,
                                              const int2* __restrict__ pairs,
                                              const u16* __restrict__ cur,
                                              u16* __restrict__ nxt) {
    size_t gid = (size_t)blockIdx.x * blockDim.x + threadIdx.x;
    int row  = (int)(gid >> 6);
    int lane = (int)(gid & 63);
    if (row >= N_NODES) return;
    const int  sl = lane & 31;
    const bool hi = lane >= 32;
    const unsigned* tab = (const unsigned*)cur;    // 32 dwords per row
    int start = rowptr[row];
    int end   = rowptr[row + 1];
    float a0 = 0.f, a1 = 0.f, b0 = 0.f, b1 = 0.f;
    int e = start;

    if ((e & 1) && e < end) {                      // align e to even
        int2 q = pairs[e];
        int   c = RFL(q.x);
        float v = __uint_as_float(RFL(q.y));
        unsigned u = tab[(size_t)c * 32 + sl];
        float vm = hi ? 0.f : v;
        a0 += vm * __uint_as_float(u << 16);
        a1 += vm * __uint_as_float(u & 0xFFFF0000u);
        ++e;
    }

    const int4* p4 = (const int4*)pairs;

#define PROC(d, x0, x1)                                                        \
    {                                                                          \
        int   ca = RFL((d).x);                                                 \
        float va = __uint_as_float(RFL((d).y));                                \
        int   cb = RFL((d).z);                                                 \
        float vb = __uint_as_float(RFL((d).w));                                \
        int   col = hi ? cb : ca;                                              \
        float vv  = hi ? vb : va;                                              \
        unsigned u = tab[(size_t)col * 32 + sl];                               \
        x0 += vv * __uint_as_float(u << 16);                                   \
        x1 += vv * __uint_as_float(u & 0xFFFF0000u);                           \
    }

    for (; e + 15 < end; e += 16) {
        int h = e >> 1;
        int4 d0 = p4[h + 0], d1 = p4[h + 1], d2 = p4[h + 2], d3 = p4[h + 3];
        int4 d4 = p4[h + 4], d5 = p4[h + 5], d6 = p4[h + 6], d7 = p4[h + 7];
        PROC(d0, a0, a1) PROC(d1, b0, b1) PROC(d2, a0, a1) PROC(d3, b0, b1)
        PROC(d4, a0, a1) PROC(d5, b0, b1) PROC(d6, a0, a1) PROC(d7, b0, b1)
    }
    for (; e + 1 < end; e += 2) {
        int4 d = p4[e >> 1];
        PROC(d, a0, a1)
    }
    if (e < end) {
        int2 q = pairs[e];
        int   c = RFL(q.x);
        float v = __uint_as_float(RFL(q.y));
        unsigned u = tab[(size_t)c * 32 + sl];
        float vm = hi ? 0.f : v;
        a0 += vm * __uint_as_float(u << 16);
        a1 += vm * __uint_as_float(u & 0xFFFF0000u);
    }
#undef PROC

    float s0 = a0 + b0, s1 = a1 + b1;
    s0 += __shfl_xor(s0, 32);
    s1 += __shfl_xor(s1, 32);
    if (!hi) {
        unsigned o = (unsigned)f2bf(s0) | ((unsigned)f2bf(s1) << 16);
        ((unsigned*)nxt)[(size_t)row * 32 + sl] = o;
    }
}

// ---------------- out = layer-0 gather from f32 originals (exact) ----------------
__global__ void k_out0(const float* __restrict__ ue, const float* __restrict__ ie,
                       const int* __restrict__ users, const int* __restrict__ pos,
                       const int* __restrict__ neg, float* __restrict__ out) {
    size_t t = (size_t)blockIdx.x * blockDim.x + threadIdx.x;
    size_t r = t >> 4;
    int sub = (int)(t & 15);
    if (r >= (size_t)(3 * BATCH_SZ)) return;
    int which = (int)(r / BATCH_SZ);
    int bi    = (int)(r % BATCH_SZ);
    int node;
    if (which == 0)      node = users[bi];
    else if (which == 1) node = N_USERS + pos[bi];
    else                 node = N_USERS + neg[bi];
    const float* src = (node < N_USERS) ? (ue + (size_t)node * EMB)
                                        : (ie + (size_t)(node - N_USERS) * EMB);
    float4 v = ((const float4*)src)[sub];
    ((float4*)(out + r * EMB))[sub] = v;
}

// ---------------- out += layer-k gather (bf16) ----------------
__global__ void k_outb(const u16* __restrict__ ego,
                       const int* __restrict__ users, const int* __restrict__ pos,
                       const int* __restrict__ neg, float* __restrict__ out) {
    size_t t = (size_t)blockIdx.x * blockDim.x + threadIdx.x;
    size_t r = t >> 4;
    int sub = (int)(t & 15);
    if (r >= (size_t)(3 * BATCH_SZ)) return;
    int which = (int)(r / BATCH_SZ);
    int bi    = (int)(r % BATCH_SZ);
    int node;
    if (which == 0)      node = users[bi];
    else if (which == 1) node = N_USERS + pos[bi];
    else                 node = N_USERS + neg[bi];
    ushort4 h = ((const ushort4*)(ego + (size_t)node * EMB))[sub];
    float4* op = (float4*)(out + r * EMB) + sub;
    float4 o = *op;
    o.x += bf2f(h.x); o.y += bf2f(h.y); o.z += bf2f(h.z); o.w += bf2f(h.w);
    *op = o;
}

// ---------------- fused layer-3 spmv (batch rows only) + final scale ----------------
__global__ __launch_bounds__(256) void k_last(const int* __restrict__ rowptr,
                                              const int2* __restrict__ pairs,
                                              const u16* __restrict__ cur,
                                              const int* __restrict__ users,
                                              const int* __restrict__ pos,
                                              const int* __restrict__ neg,
                                              float* __restrict__ out) {
    size_t gid = (size_t)blockIdx.x * blockDim.x + threadIdx.x;
    int r    = (int)(gid >> 6);
    int lane = (int)(gid & 63);
    if (r >= 3 * BATCH_SZ) return;
    int which = r / BATCH_SZ;
    int bi    = r % BATCH_SZ;
    int node;
    if (which == 0)      node = users[bi];
    else if (which == 1) node = N_USERS + pos[bi];
    else                 node = N_USERS + neg[bi];
    int start = rowptr[node];
    int end   = rowptr[node + 1];
    float a0 = 0.f, a1 = 0.f, a2 = 0.f, a3 = 0.f;
    int e = start;
    for (; e + 3 < end; e += 4) {
        int2 q0 = pairs[e], q1 = pairs[e + 1], q2 = pairs[e + 2], q3 = pairs[e + 3];
        int   c0 = RFL(q0.x);
        float v0 = __uint_as_float(RFL(q0.y));
        int   c1 = RFL(q1.x);
        float v1 = __uint_as_float(RFL(q1.y));
        int   c2 = RFL(q2.x);
        float v2 = __uint_as_float(RFL(q2.y));
        int   c3 = RFL(q3.x);
        float v3 = __uint_as_float(RFL(q3.y));
        a0 += v0 * bf2f(cur[(size_t)c0 * EMB + lane]);
        a1 += v1 * bf2f(cur[(size_t)c1 * EMB + lane]);
        a2 += v2 * bf2f(cur[(size_t)c2 * EMB + lane]);
        a3 += v3 * bf2f(cur[(size_t)c3 * EMB + lane]);
    }
    for (; e < end; ++e) {
        int2 q = pairs[e];
        int   c = RFL(q.x);
        float v = __uint_as_float(RFL(q.y));
        a0 += v * bf2f(cur[(size_t)c * EMB + lane]);
    }
    float sum = (a0 + a1) + (a2 + a3);
    size_t oi = (size_t)r * EMB + lane;
    out[oi] = (out[oi] + sum) * 0.25f;
}

extern "C" void kernel_launch(void* const* d_in, const int* in_sizes, int n_in,
                              void* d_out, int out_size, void* d_ws, size_t ws_size,
                              hipStream_t stream) {
    const int*   erow  = (const int*)  d_in[0];
    const int*   ecol  = (const int*)  d_in[1];
    const float* eval_ = (const float*)d_in[2];
    const float* ue    = (const float*)d_in[3];
    const float* ie    = (const float*)d_in[4];
    const int*   users = (const int*)  d_in[5];
    const int*   pos   = (const int*)  d_in[6];
    const int*   neg   = (const int*)  d_in[7];
    float* out = (float*)d_out;

    char* ws = (char*)d_ws;
    const size_t tblB  = (size_t)150016 * EMB * sizeof(u16);       // 19,202,048 B
    const size_t pairB = (size_t)NNZ_TOT * sizeof(int2);           // 38,400,000 B
    u16*  ego0   = (u16*)(ws);
    u16*  ego1   = (u16*)(ws + tblB);
    int2* pairsA = (int2*)(ws);
    int2* pairsB = (int2*)(ws + 2 * tblB);
    int*  off_t  = (int*) (ws + 2 * tblB + pairB);
    int*  rowptr = off_t + (size_t)(NB + 1) * CHUNKS;
    int*  bucketCnt = rowptr + ((N_NODES + 1 + 63) & ~63);
    int*  bbase     = bucketCnt + NB;

    const int blk = 256;

    k_zero<<<(NB + blk - 1) / blk, blk, 0, stream>>>(bucketCnt, NB);
    k_bin<<<CHUNKS, 1024, 0, stream>>>(erow, ecol, eval_, pairsA, off_t, bucketCnt);
    k_bscan<<<1, 1024, 0, stream>>>(bucketCnt, bbase, rowptr);
    k_sort<<<NB, blk, 0, stream>>>(off_t, pairsA, bbase, pairsB, rowptr);

    const size_t n4 = (size_t)N_NODES * EMB / 4;
    k_init<<<(int)((n4 + blk - 1) / blk), blk, 0, stream>>>(ue, ie, ego0);

    const int grid_g = (int)(((size_t)3 * BATCH_SZ * 16 + blk - 1) / blk);
    k_out0<<<grid_g, blk, 0, stream>>>(ue, ie, users, pos, neg, out);

    const size_t spmv_threads = (size_t)N_NODES * 64;
    const int grid_spmv = (int)((spmv_threads + blk - 1) / blk);
    k_spmv<<<grid_spmv, blk, 0, stream>>>(rowptr, pairsB, ego0, ego1);
    k_outb<<<grid_g, blk, 0, stream>>>(ego1, users, pos, neg, out);
    k_spmv<<<grid_spmv, blk, 0, stream>>>(rowptr, pairsB, ego1, ego0);
    k_outb<<<grid_g, blk, 0, stream>>>(ego0, users, pos, neg, out);

    const size_t lth = (size_t)3 * BATCH_SZ * 64;
    k_last<<<(int)((lth + blk - 1) / blk), blk, 0, stream>>>(rowptr, pairsB, ego0,
                                                             users, pos, neg, out);
}

// Round 10
// 468.665 us; speedup vs baseline: 11.0012x; 1.0533x over previous
//
#include <hip/hip_runtime.h>

#define N_USERS 100000
#define N_ITEMS 50000
#define N_NODES 150000
#define EMB 64
#define NNZ_TOT 4800000
#define BATCH_SZ 4096

#define BROWS 64                  // rows per bucket
#define NB 2344                   // ceil(150000/64)
#define CHUNKS 512
#define CHUNKE 9375               // NNZ_TOT / CHUNKS (exact)
#define SBUF 3072                 // LDS sort buffer (bucket mean 2048, ~22 sigma)
#define KBINS 2048                // sort key bins
#define BIN_LDS (2 * NB * 4 + CHUNKE * 8)   // 93,752 B dynamic LDS for k_bin

typedef unsigned short u16;

static __device__ __forceinline__ u16 f2bf(float f) {
    unsigned u = __float_as_uint(f);
    unsigned r = u + 0x7FFFu + ((u >> 16) & 1u);   // RNE
    return (u16)(r >> 16);
}
static __device__ __forceinline__ float bf2f(u16 h) {
    return __uint_as_float(((unsigned)h) << 16);
}

// ---------------- ego0 (bf16) = concat(user, item) ----------------
__global__ void k_init(const float* __restrict__ ue, const float* __restrict__ ie,
                       u16* __restrict__ ego) {
    size_t i = (size_t)blockIdx.x * blockDim.x + threadIdx.x;
    const size_t n4 = (size_t)N_NODES * EMB / 4;
    if (i >= n4) return;
    const size_t u4 = (size_t)N_USERS * EMB / 4;
    float4 v = (i < u4) ? ((const float4*)ue)[i] : ((const float4*)ie)[i - u4];
    ushort4 o;
    o.x = f2bf(v.x); o.y = f2bf(v.y); o.z = f2bf(v.z); o.w = f2bf(v.w);
    ((ushort4*)ego)[i] = o;
}

__global__ void k_zero(int* __restrict__ p, int n) {
    int i = blockIdx.x * blockDim.x + threadIdx.x;
    if (i < n) p[i] = 0;
}

// ---- per-chunk counting-sort into 64-row buckets, LDS-staged (coalesced writes) ----
__global__ __launch_bounds__(1024) void k_bin(const int* __restrict__ erow,
                                              const int* __restrict__ ecol,
                                              const float* __restrict__ eval_,
                                              int2* __restrict__ pairsA,
                                              int* __restrict__ off_t,     // [(NB+1)][CHUNKS]
                                              int* __restrict__ bucketCnt) {
    extern __shared__ int smem[];
    int*  hist = smem;                 // NB
    int*  fill = smem + NB;            // NB
    int2* buf  = (int2*)(smem + 2 * NB); // CHUNKE edges
    const int c = blockIdx.x;
    const int cbase = c * CHUNKE;
    const int tid = threadIdx.x;

    for (int i = tid; i < NB; i += 1024) hist[i] = 0;
    __syncthreads();

    // pass 1: bucket histogram
    for (int i = tid; i < CHUNKE; i += 1024)
        atomicAdd(&hist[erow[cbase + i] >> 6], 1);
    __syncthreads();

    // exclusive scan of hist -> fill (wave 0)
    if (tid < 64) {
        int carry = 0;
        for (int blk = 0; blk < (NB + 63) / 64; ++blk) {
            int idx = blk * 64 + tid;
            int v = (idx < NB) ? hist[idx] : 0;
            int s = v;
            #pragma unroll
            for (int o = 1; o < 64; o <<= 1) {
                int t = __shfl_up(s, o);
                if (tid >= o) s += t;
            }
            if (idx < NB) fill[idx] = s - v + carry;
            carry += __shfl(s, 63);
        }
    }
    __syncthreads();

    // publish transposed segment starts + bucket totals
    for (int i = tid; i < NB; i += 1024) {
        off_t[i * CHUNKS + c] = cbase + fill[i];
        atomicAdd(&bucketCnt[i], hist[i]);
    }
    if (tid == 0) off_t[NB * CHUNKS + c] = cbase + CHUNKE;
    __syncthreads();

    // pass 2: scatter packed (row_local<<18 | col, val) INTO LDS
    for (int i = tid; i < CHUNKE; i += 1024) {
        int e = cbase + i;
        int r = erow[e];
        int bb = r >> 6;
        int p = atomicAdd(&fill[bb], 1);
        int2 pr;
        pr.x = ((r & 63) << 18) | ecol[e];
        pr.y = __float_as_int(eval_[e]);
        buf[p] = pr;
    }
    __syncthreads();

    // flush sequentially -> fully coalesced global writes
    for (int i = tid; i < CHUNKE; i += 1024)
        pairsA[cbase + i] = buf[i];
}

// ---------------- scan bucket counts -> bucket_base[0..NB] ----------------
__global__ __launch_bounds__(1024) void k_bscan(const int* __restrict__ cnt,
                                                int* __restrict__ bbase,
                                                int* __restrict__ rowptr) {
    __shared__ int lds[1024];
    const int tid = threadIdx.x;
    int vals[3];
    int local = 0;
    #pragma unroll
    for (int j = 0; j < 3; ++j) {
        int idx = tid * 3 + j;
        int v = (idx < NB) ? cnt[idx] : 0;
        vals[j] = local;
        local += v;
    }
    lds[tid] = local;
    __syncthreads();
    for (int off = 1; off < 1024; off <<= 1) {
        int t = (tid >= off) ? lds[tid - off] : 0;
        __syncthreads();
        lds[tid] += t;
        __syncthreads();
    }
    int excl = lds[tid] - local;
    #pragma unroll
    for (int j = 0; j < 3; ++j) {
        int idx = tid * 3 + j;
        if (idx <= NB) {
            int b = excl + vals[j];
            bbase[idx] = b;
            if (idx == NB) rowptr[N_NODES] = b;   // == NNZ_TOT
        }
    }
}

// ---- per-bucket LDS sort by (row_local, col-tile) -> row-sorted CSR ----
__global__ __launch_bounds__(256) void k_sort(const int* __restrict__ off_t,
                                              const int2* __restrict__ pairsA,
                                              const int* __restrict__ bbase,
                                              int2* __restrict__ pairsB,
                                              int* __restrict__ rowptr) {
    __shared__ int hist[KBINS];
    __shared__ int fillx[KBINS];
    __shared__ int2 buf[SBUF];
    __shared__ int wsum[4];
    const int b = blockIdx.x;
    const int tid = threadIdx.x, lane = tid & 63, w = tid >> 6;

    // two chunk-segments per thread (512 chunks, 256 threads)
    const int s0 = off_t[b * CHUNKS + tid];
    const int e0 = off_t[(b + 1) * CHUNKS + tid];
    const int s1 = off_t[b * CHUNKS + tid + 256];
    const int e1 = off_t[(b + 1) * CHUNKS + tid + 256];
    const int l0 = e0 - s0;
    const int len = l0 + (e1 - s1);

    for (int i = tid; i < KBINS; i += 256) hist[i] = 0;

    int sc = len;
    #pragma unroll
    for (int o = 1; o < 64; o <<= 1) {
        int t = __shfl_up(sc, o);
        if (lane >= o) sc += t;
    }
    if (lane == 63) wsum[w] = sc;
    __syncthreads();
    int wbase = 0;
    for (int i = 0; i < w; ++i) wbase += wsum[i];
    int tbase = wbase + sc - len;

    for (int i = 0; i < len; ++i) {
        int2 p = (i < l0) ? pairsA[s0 + i] : pairsA[s1 + (i - l0)];
        int dst = tbase + i;
        if (dst < SBUF) buf[dst] = p;
        atomicAdd(&hist[(p.x >> 13) & (KBINS - 1)], 1);
    }
    __syncthreads();

    const int base = bbase[b];
    if (tid < 64) {
        int carry = 0;
        for (int blk = 0; blk < KBINS / 64; ++blk) {
            int idx = blk * 64 + tid;
            int v = hist[idx];
            int s2 = v;
            #pragma unroll
            for (int o = 1; o < 64; o <<= 1) {
                int t = __shfl_up(s2, o);
                if (tid >= o) s2 += t;
            }
            int excl = s2 - v + carry;
            fillx[idx] = excl;
            if ((idx & 31) == 0) {
                int node = b * BROWS + (idx >> 5);
                if (node < N_NODES) rowptr[node] = base + excl;
            }
            carry += __shfl(s2, 63);
        }
    }
    __syncthreads();

    int total = bbase[b + 1] - base;
    if (total > SBUF) total = SBUF;
    for (int i = tid; i < total; i += 256) {
        int2 p = buf[i];
        int pos = atomicAdd(&fillx[(p.x >> 13) & (KBINS - 1)], 1);
        pairsB[base + pos] = make_int2(p.x & 0x3FFFF, p.y);
    }
}

// ---- SpMV: wave per row; 2 edges per wave-gather; no RFL; 32-bit saddr offsets ----
__global__ __launch_bounds__(256) void k_spmv(const int* __restrict__ rowptr,
                                              const int2* __restrict__ pairs,
                                              const u16* __restrict__ cur,
                                              u16* __restrict__ nxt) {
    size_t gid = (size_t)blockIdx.x * blockDim.x + threadIdx.x;
    int row  = (int)(gid >> 6);
    int lane = (int)(gid & 63);
    if (row >= N_NODES) return;
    const int      sl  = lane & 31;
    const bool     hi  = lane >= 32;
    const unsigned sl4 = (unsigned)sl << 2;
    const char* tab = (const char*)cur;            // 128 B per row
    int start = rowptr[row];
    int end   = rowptr[row + 1];
    float a0 = 0.f, a1 = 0.f, b0 = 0.f, b1 = 0.f;
    int e = start;

    if ((e & 1) && e < end) {                      // align e to even
        int2 q = pairs[e];
        unsigned col = (unsigned)q.x;
        float v = __uint_as_float((unsigned)q.y);
        unsigned u = *(const unsigned*)(tab + (size_t)((col << 7) | sl4));
        float vm = hi ? 0.f : v;
        a0 += vm * __uint_as_float(u << 16);
        a1 += vm * __uint_as_float(u & 0xFFFF0000u);
        ++e;
    }

    const int4* p4 = (const int4*)pairs;

#define PROC(d, x0, x1)                                                        \
    {                                                                          \
        unsigned col = (unsigned)(hi ? (d).z : (d).x);                         \
        float    vv  = __uint_as_float((unsigned)(hi ? (d).w : (d).y));        \
        unsigned u = *(const unsigned*)(tab + (size_t)((col << 7) | sl4));     \
        x0 += vv * __uint_as_float(u << 16);                                   \
        x1 += vv * __uint_as_float(u & 0xFFFF0000u);                           \
    }

    for (; e + 15 < end; e += 16) {
        int h = e >> 1;
        int4 d0 = p4[h + 0], d1 = p4[h + 1], d2 = p4[h + 2], d3 = p4[h + 3];
        int4 d4 = p4[h + 4], d5 = p4[h + 5], d6 = p4[h + 6], d7 = p4[h + 7];
        PROC(d0, a0, a1) PROC(d1, b0, b1) PROC(d2, a0, a1) PROC(d3, b0, b1)
        PROC(d4, a0, a1) PROC(d5, b0, b1) PROC(d6, a0, a1) PROC(d7, b0, b1)
    }
    for (; e + 1 < end; e += 2) {
        int4 d = p4[e >> 1];
        PROC(d, a0, a1)
    }
    if (e < end) {
        int2 q = pairs[e];
        unsigned col = (unsigned)q.x;
        float v = __uint_as_float((unsigned)q.y);
        unsigned u = *(const unsigned*)(tab + (size_t)((col << 7) | sl4));
        float vm = hi ? 0.f : v;
        a0 += vm * __uint_as_float(u << 16);
        a1 += vm * __uint_as_float(u & 0xFFFF0000u);
    }
#undef PROC

    float s0 = a0 + b0, s1 = a1 + b1;
    s0 += __shfl_xor(s0, 32);
    s1 += __shfl_xor(s1, 32);
    if (!hi) {
        unsigned o = (unsigned)f2bf(s0) | ((unsigned)f2bf(s1) << 16);
        ((unsigned*)nxt)[(size_t)row * 32 + sl] = o;
    }
}

// ---------------- out = layer-0 gather from f32 originals (exact) ----------------
__global__ void k_out0(const float* __restrict__ ue, const float* __restrict__ ie,
                       const int* __restrict__ users, const int* __restrict__ pos,
                       const int* __restrict__ neg, float* __restrict__ out) {
    size_t t = (size_t)blockIdx.x * blockDim.x + threadIdx.x;
    size_t r = t >> 4;
    int sub = (int)(t & 15);
    if (r >= (size_t)(3 * BATCH_SZ)) return;
    int which = (int)(r / BATCH_SZ);
    int bi    = (int)(r % BATCH_SZ);
    int node;
    if (which == 0)      node = users[bi];
    else if (which == 1) node = N_USERS + pos[bi];
    else                 node = N_USERS + neg[bi];
    const float* src = (node < N_USERS) ? (ue + (size_t)node * EMB)
                                        : (ie + (size_t)(node - N_USERS) * EMB);
    float4 v = ((const float4*)src)[sub];
    ((float4*)(out + r * EMB))[sub] = v;
}

// ---------------- out += layer-k gather (bf16) ----------------
__global__ void k_outb(const u16* __restrict__ ego,
                       const int* __restrict__ users, const int* __restrict__ pos,
                       const int* __restrict__ neg, float* __restrict__ out) {
    size_t t = (size_t)blockIdx.x * blockDim.x + threadIdx.x;
    size_t r = t >> 4;
    int sub = (int)(t & 15);
    if (r >= (size_t)(3 * BATCH_SZ)) return;
    int which = (int)(r / BATCH_SZ);
    int bi    = (int)(r % BATCH_SZ);
    int node;
    if (which == 0)      node = users[bi];
    else if (which == 1) node = N_USERS + pos[bi];
    else                 node = N_USERS + neg[bi];
    ushort4 h = ((const ushort4*)(ego + (size_t)node * EMB))[sub];
    float4* op = (float4*)(out + r * EMB) + sub;
    float4 o = *op;
    o.x += bf2f(h.x); o.y += bf2f(h.y); o.z += bf2f(h.z); o.w += bf2f(h.w);
    *op = o;
}

// ---------------- fused layer-3 spmv (batch rows only) + final scale ----------------
#define RFL(x) __builtin_amdgcn_readfirstlane(x)
__global__ __launch_bounds__(256) void k_last(const int* __restrict__ rowptr,
                                              const int2* __restrict__ pairs,
                                              const u16* __restrict__ cur,
                                              const int* __restrict__ users,
                                              const int* __restrict__ pos,
                                              const int* __restrict__ neg,
                                              float* __restrict__ out) {
    size_t gid = (size_t)blockIdx.x * blockDim.x + threadIdx.x;
    int r    = (int)(gid >> 6);
    int lane = (int)(gid & 63);
    if (r >= 3 * BATCH_SZ) return;
    int which = r / BATCH_SZ;
    int bi    = r % BATCH_SZ;
    int node;
    if (which == 0)      node = users[bi];
    else if (which == 1) node = N_USERS + pos[bi];
    else                 node = N_USERS + neg[bi];
    int start = rowptr[node];
    int end   = rowptr[node + 1];
    float a0 = 0.f, a1 = 0.f, a2 = 0.f, a3 = 0.f;
    int e = start;
    for (; e + 3 < end; e += 4) {
        int2 q0 = pairs[e], q1 = pairs[e + 1], q2 = pairs[e + 2], q3 = pairs[e + 3];
        int   c0 = RFL(q0.x);
        float v0 = __uint_as_float(RFL(q0.y));
        int   c1 = RFL(q1.x);
        float v1 = __uint_as_float(RFL(q1.y));
        int   c2 = RFL(q2.x);
        float v2 = __uint_as_float(RFL(q2.y));
        int   c3 = RFL(q3.x);
        float v3 = __uint_as_float(RFL(q3.y));
        a0 += v0 * bf2f(cur[(size_t)c0 * EMB + lane]);
        a1 += v1 * bf2f(cur[(size_t)c1 * EMB + lane]);
        a2 += v2 * bf2f(cur[(size_t)c2 * EMB + lane]);
        a3 += v3 * bf2f(cur[(size_t)c3 * EMB + lane]);
    }
    for (; e < end; ++e) {
        int2 q = pairs[e];
        int   c = RFL(q.x);
        float v = __uint_as_float(RFL(q.y));
        a0 += v * bf2f(cur[(size_t)c * EMB + lane]);
    }
    float sum = (a0 + a1) + (a2 + a3);
    size_t oi = (size_t)r * EMB + lane;
    out[oi] = (out[oi] + sum) * 0.25f;
}

extern "C" void kernel_launch(void* const* d_in, const int* in_sizes, int n_in,
                              void* d_out, int out_size, void* d_ws, size_t ws_size,
                              hipStream_t stream) {
    const int*   erow  = (const int*)  d_in[0];
    const int*   ecol  = (const int*)  d_in[1];
    const float* eval_ = (const float*)d_in[2];
    const float* ue    = (const float*)d_in[3];
    const float* ie    = (const float*)d_in[4];
    const int*   users = (const int*)  d_in[5];
    const int*   pos   = (const int*)  d_in[6];
    const int*   neg   = (const int*)  d_in[7];
    float* out = (float*)d_out;

    char* ws = (char*)d_ws;
    const size_t tblB  = (size_t)150016 * EMB * sizeof(u16);       // 19,202,048 B
    const size_t pairB = (size_t)NNZ_TOT * sizeof(int2);           // 38,400,000 B
    u16*  ego0   = (u16*)(ws);
    u16*  ego1   = (u16*)(ws + tblB);
    int2* pairsA = (int2*)(ws);                                    // aliases ego0/ego1
    int2* pairsB = (int2*)(ws + 2 * tblB);
    int*  off_t  = (int*) (ws + 2 * tblB + pairB);                 // (NB+1)*CHUNKS ints
    int*  rowptr = off_t + (size_t)(NB + 1) * CHUNKS;
    int*  bucketCnt = rowptr + ((N_NODES + 1 + 63) & ~63);
    int*  bbase     = bucketCnt + NB;

    const int blk = 256;

    // opt-in to >64KB dynamic LDS for k_bin (idempotent, deterministic)
    hipFuncSetAttribute(reinterpret_cast<const void*>(k_bin),
                        hipFuncAttributeMaxDynamicSharedMemorySize, BIN_LDS);

    k_zero<<<(NB + blk - 1) / blk, blk, 0, stream>>>(bucketCnt, NB);
    k_bin<<<CHUNKS, 1024, BIN_LDS, stream>>>(erow, ecol, eval_, pairsA, off_t, bucketCnt);
    k_bscan<<<1, 1024, 0, stream>>>(bucketCnt, bbase, rowptr);
    k_sort<<<NB, blk, 0, stream>>>(off_t, pairsA, bbase, pairsB, rowptr);

    const size_t n4 = (size_t)N_NODES * EMB / 4;
    k_init<<<(int)((n4 + blk - 1) / blk), blk, 0, stream>>>(ue, ie, ego0);

    const int grid_g = (int)(((size_t)3 * BATCH_SZ * 16 + blk - 1) / blk);
    k_out0<<<grid_g, blk, 0, stream>>>(ue, ie, users, pos, neg, out);

    const size_t spmv_threads = (size_t)N_NODES * 64;
    const int grid_spmv = (int)((spmv_threads + blk - 1) / blk);
    k_spmv<<<grid_spmv, blk, 0, stream>>>(rowptr, pairsB, ego0, ego1);
    k_outb<<<grid_g, blk, 0, stream>>>(ego1, users, pos, neg, out);
    k_spmv<<<grid_spmv, blk, 0, stream>>>(rowptr, pairsB, ego1, ego0);
    k_outb<<<grid_g, blk, 0, stream>>>(ego0, users, pos, neg, out);

    const size_t lth = (size_t)3 * BATCH_SZ * 64;
    k_last<<<(int)((lth + blk - 1) / blk), blk, 0, stream>>>(rowptr, pairsB, ego0,
                                                             users, pos, neg, out);
}